// Round 1
// baseline (196.260 us; speedup 1.0000x reference)
//
#include <hip/hip_runtime.h>
#include <hip/hip_bf16.h>

#define B_ 2
#define C_ 1024
#define S_ 2048
#define H_ 16
#define KDIM 1024

typedef __attribute__((ext_vector_type(8))) short short8_t;
typedef __attribute__((ext_vector_type(4))) float f32x4;

__device__ __forceinline__ void glds16(const void* g, void* l) {
  __builtin_amdgcn_global_load_lds((const __attribute__((address_space(1))) void*)g,
                                   (__attribute__((address_space(3))) void*)l, 16, 0, 0);
}

__device__ __forceinline__ unsigned short f2bf(float f) {
  __hip_bfloat16 h = __float2bfloat16(f);
  return __builtin_bit_cast(unsigned short, h);
}

// ---------------- weight fp32 -> bf16 ----------------
__global__ __launch_bounds__(256) void cvt_w(const float* __restrict__ w,
                                             unsigned short* __restrict__ o) {
  int i = blockIdx.x * 256 + threadIdx.x;           // 262144 float4s
  float4 v = ((const float4*)w)[i];
  short4 r;
  r.x = (short)f2bf(v.x); r.y = (short)f2bf(v.y);
  r.z = (short)f2bf(v.z); r.w = (short)f2bf(v.w);
  ((short4*)o)[i] = r;
}

// ---------------- per-batch stats (two-stage, deterministic) ----------------
__global__ __launch_bounds__(256) void stats1(const float* __restrict__ x,
                                              float2* __restrict__ part) {
  int bid = blockIdx.x;                             // 512 blocks
  int b = bid >> 8, chunk = bid & 255;
  const float4* p = (const float4*)(x + (size_t)b*(C_*S_) + (size_t)chunk*8192);
  int t = threadIdx.x;
  float s = 0.f, q = 0.f;
#pragma unroll
  for (int i = 0; i < 8; ++i) {
    float4 v = p[t + i*256];
    s += v.x + v.y + v.z + v.w;
    q += v.x*v.x + v.y*v.y + v.z*v.z + v.w*v.w;
  }
#pragma unroll
  for (int d = 1; d < 64; d <<= 1) { s += __shfl_xor(s, d); q += __shfl_xor(q, d); }
  __shared__ float2 wsum[4];
  if ((t & 63) == 0) wsum[t >> 6] = make_float2(s, q);
  __syncthreads();
  if (t == 0) {
    float S = 0.f, Q = 0.f;
    for (int i = 0; i < 4; ++i) { S += wsum[i].x; Q += wsum[i].y; }
    part[bid] = make_float2(S, Q);
  }
}

__global__ __launch_bounds__(256) void stats2(const float2* __restrict__ part,
                                              float* __restrict__ stats) {
  int b = blockIdx.x;
  int t = threadIdx.x;
  float2 v = part[b*256 + t];
  float s = v.x, q = v.y;
#pragma unroll
  for (int d = 1; d < 64; d <<= 1) { s += __shfl_xor(s, d); q += __shfl_xor(q, d); }
  __shared__ float2 wsum[4];
  if ((t & 63) == 0) wsum[t >> 6] = make_float2(s, q);
  __syncthreads();
  if (t == 0) {
    float S = 0.f, Q = 0.f;
    for (int i = 0; i < 4; ++i) { S += wsum[i].x; Q += wsum[i].y; }
    const float invN = 1.0f / (float)(C_*S_);
    float mean = S * invN;
    float var = Q * invN - mean*mean;
    stats[b*2]   = mean;
    stats[b*2+1] = rsqrtf(var + 1e-5f);
  }
}

// ---------------- normalize + transpose (B,C,S)f32 -> (B,S,C)bf16 ----------------
__global__ __launch_bounds__(256) void normt(const float* __restrict__ x,
                                             const float* __restrict__ gw,
                                             const float* __restrict__ gb,
                                             const float* __restrict__ stats,
                                             unsigned short* __restrict__ xt) {
  __shared__ short lds[64*72];
  int bid = blockIdx.x;                              // 1024 blocks
  int b = bid >> 9, rem = bid & 511;
  int ct = rem >> 5, st = rem & 31;
  float mean = stats[b*2], rstd = stats[b*2+1];
  int t = threadIdx.x;
  int r = t >> 2, seg = t & 3;
  int c = ct*64 + r;
  float wsc = gw[c] * rstd;
  float bof = gb[c] - mean * wsc;
  const float4* src = (const float4*)(x + (size_t)b*(C_*S_) + (size_t)c*S_ + st*64 + seg*16);
#pragma unroll
  for (int j = 0; j < 4; ++j) {
    float4 v = src[j];
    int sl = seg*16 + j*4;
    lds[(sl+0)*72 + r] = (short)f2bf(v.x*wsc + bof);
    lds[(sl+1)*72 + r] = (short)f2bf(v.y*wsc + bof);
    lds[(sl+2)*72 + r] = (short)f2bf(v.z*wsc + bof);
    lds[(sl+3)*72 + r] = (short)f2bf(v.w*wsc + bof);
  }
  __syncthreads();
  int sl = t >> 2;
  __attribute__((aligned(16))) unsigned short tmp[16];
#pragma unroll
  for (int j = 0; j < 16; ++j) tmp[j] = (unsigned short)lds[sl*72 + seg*16 + j];
  unsigned short* dst = xt + ((size_t)b*S_ + st*64 + sl) * C_ + ct*64 + seg*16;
  *(short8_t*)dst       = *(const short8_t*)tmp;
  *(short8_t*)(dst + 8) = *(const short8_t*)(tmp + 8);
}

// ---------------- NT GEMM: C[m,n] = sum_k A[m,k]*B[n,k] (K=1024) ----------------
// BM=64, BN=128, BK=64; 4 waves, wave w owns m[0:64) x n[w*32:(w+1)*32)
// EPI 0: out bf16 (B,H,S,D), bias[gn]   (gm=(b,s), gn=(h,d))
// EPI 1: out bf16 (B,C,S) "rows=c_out", bias[gm]  (gm=c_out, gn=(b,s))
// EPI 2: out f32  (B,C,S) + bias[gm] + resid
template<int EPI>
__global__ __launch_bounds__(256)
void gemm_nt(const unsigned short* __restrict__ A,
             const unsigned short* __restrict__ Bm,
             const float* __restrict__ bias,
             const float* __restrict__ resid,
             void* __restrict__ outp,
             int nbn) {
  __shared__ __attribute__((aligned(16))) short As[64*64];
  __shared__ __attribute__((aligned(16))) short Bs[128*64];
  int nwg = gridDim.x;
  int bid = blockIdx.x;
  int cpx = nwg >> 3;                                // grid % 8 == 0
  int sbid = (bid & 7) * cpx + (bid >> 3);
  int bm = sbid / nbn, bn = sbid % nbn;
  int m0 = bm << 6, n0 = bn << 7;
  int t = threadIdx.x;
  int l = t & 63, wid = t >> 6;

  int r_st = t >> 3;                                 // 0..31
  int slot_src = (t & 7) ^ (r_st & 7);               // pre-swizzled source slot
  const unsigned short* a_src = A + (size_t)(m0 + r_st) * KDIM + slot_src * 8;
  const unsigned short* b_src = Bm + (size_t)(n0 + r_st) * KDIM + slot_src * 8;
  char* As_base = (char*)As + wid*1024;
  char* Bs_base = (char*)Bs + wid*1024;

  f32x4 acc[4][2] = {};

  for (int kt = 0; kt < KDIM; kt += 64) {
    __syncthreads();
    glds16(a_src + kt, As_base);
    glds16(a_src + (size_t)32*KDIM + kt, As_base + 4096);
#pragma unroll
    for (int i = 0; i < 4; ++i)
      glds16(b_src + (size_t)(i*32)*KDIM + kt, Bs_base + i*4096);
    __syncthreads();
#pragma unroll
    for (int kk = 0; kk < 2; ++kk) {
      short8_t af[4], bfr[2];
#pragma unroll
      for (int mi = 0; mi < 4; ++mi) {
        int row = mi*16 + (l & 15);
        int slot = (kk*4 + (l >> 4)) ^ (row & 7);
        af[mi] = *(const short8_t*)((const char*)As + row*128 + slot*16);
      }
#pragma unroll
      for (int ni = 0; ni < 2; ++ni) {
        int row = wid*32 + ni*16 + (l & 15);
        int slot = (kk*4 + (l >> 4)) ^ (row & 7);
        bfr[ni] = *(const short8_t*)((const char*)Bs + row*128 + slot*16);
      }
#pragma unroll
      for (int mi = 0; mi < 4; ++mi)
#pragma unroll
        for (int ni = 0; ni < 2; ++ni)
          acc[mi][ni] = __builtin_amdgcn_mfma_f32_16x16x32_bf16(af[mi], bfr[ni], acc[mi][ni], 0, 0, 0);
    }
  }

#pragma unroll
  for (int mi = 0; mi < 4; ++mi) {
#pragma unroll
    for (int ni = 0; ni < 2; ++ni) {
#pragma unroll
      for (int r = 0; r < 4; ++r) {
        int gm = m0 + mi*16 + ((l >> 4) << 2) + r;
        int gn = n0 + wid*32 + ni*16 + (l & 15);
        float v = acc[mi][ni][r];
        if (EPI == 0) {
          v += bias[gn];
          size_t off = ((size_t)((gm >> 11)*H_ + (gn >> 6)) * S_ + (gm & 2047)) * 64 + (gn & 63);
          ((unsigned short*)outp)[off] = f2bf(v);
        } else {
          v += bias[gm];
          size_t off = (size_t)(gn >> 11) * ((size_t)C_*S_) + (size_t)gm * S_ + (gn & 2047);
          if (EPI == 1) {
            ((unsigned short*)outp)[off] = f2bf(v);
          } else {
            ((float*)outp)[off] = v + resid[off];
          }
        }
      }
    }
  }
}

// ---------------- flash attention ----------------
// Q,K: (B,H,S,D) bf16; Vt: (B,H,D,S) bf16; out: (B,S,C) bf16
// 4 waves x 16 q-rows (QBLK=64), KBLK=64, online softmax in log2 domain
__global__ __launch_bounds__(256)
void attn_kernel(const unsigned short* __restrict__ Q,
                 const unsigned short* __restrict__ Kt,
                 const unsigned short* __restrict__ Vt,
                 const int* __restrict__ mask,
                 unsigned short* __restrict__ outp) {
  __shared__ __attribute__((aligned(16))) short Ks[64*64];
  __shared__ __attribute__((aligned(16))) short Vs[64*64];
  __shared__ __attribute__((aligned(16))) short Ps[4][16*72];

  int bid = blockIdx.x;                              // 1024 blocks
  int bh = bid >> 5, qt = bid & 31;
  int b = bh >> 4, h = bh & 15;
  int t = threadIdx.x, l = t & 63, wid = t >> 6;

  int qrow = qt*64 + wid*16 + (l & 15);
  const unsigned short* qp = Q + ((size_t)bh * S_ + qrow) * 64 + (l >> 4) * 8;
  short8_t qf0 = *(const short8_t*)qp;
  short8_t qf1 = *(const short8_t*)(qp + 32);

  float m_run[4], l_run[4];
  f32x4 oacc[4] = {};
#pragma unroll
  for (int r = 0; r < 4; ++r) { m_run[r] = -1e30f; l_run[r] = 0.f; }

  int r_st = t >> 3;
  int slot_src = (t & 7) ^ (r_st & 7);
  const unsigned short* ksrc = Kt + ((size_t)bh * S_ + r_st) * 64 + slot_src * 8;
  const unsigned short* vsrc = Vt + ((size_t)bh * 64 + r_st) * S_ + slot_src * 8;
  char* Ks_base = (char*)Ks + wid*1024;
  char* Vs_base = (char*)Vs + wid*1024;

  const float SC = 0.18033688011112042f;             // (1/8) * log2(e)
  const int* mrow = mask + b * S_;

  for (int kt0 = 0; kt0 < S_; kt0 += 64) {
    __syncthreads();
#pragma unroll
    for (int i = 0; i < 2; ++i) {
      glds16(ksrc + (size_t)(kt0 + i*32) * 64, Ks_base + i*4096);
      glds16(vsrc + (size_t)(i*32) * S_ + kt0, Vs_base + i*4096);
    }
    __syncthreads();

    f32x4 sacc[4] = {};
#pragma unroll
    for (int kn = 0; kn < 4; ++kn) {
      int row = kn*16 + (l & 15);
      int slot0 = ((l >> 4)) ^ (row & 7);
      int slot1 = (4 + (l >> 4)) ^ (row & 7);
      short8_t kf0 = *(const short8_t*)((const char*)Ks + row*128 + slot0*16);
      short8_t kf1 = *(const short8_t*)((const char*)Ks + row*128 + slot1*16);
      sacc[kn] = __builtin_amdgcn_mfma_f32_16x16x32_bf16(qf0, kf0, sacc[kn], 0, 0, 0);
      sacc[kn] = __builtin_amdgcn_mfma_f32_16x16x32_bf16(qf1, kf1, sacc[kn], 0, 0, 0);
    }

    float madd[4];
#pragma unroll
    for (int kn = 0; kn < 4; ++kn)
      madd[kn] = (mrow[kt0 + kn*16 + (l & 15)] == 0) ? -1e30f : 0.f;

    float p[4][4];
    float fac[4];
#pragma unroll
    for (int r = 0; r < 4; ++r) {
      float mx = -1e30f;
#pragma unroll
      for (int kn = 0; kn < 4; ++kn) {
        float s = sacc[kn][r] * SC + madd[kn];
        p[kn][r] = s;
        mx = fmaxf(mx, s);
      }
#pragma unroll
      for (int d = 1; d < 16; d <<= 1) mx = fmaxf(mx, __shfl_xor(mx, d));
      float nm = fmaxf(m_run[r], mx);
      fac[r] = exp2f(m_run[r] - nm);
      m_run[r] = nm;
      float rs = 0.f;
#pragma unroll
      for (int kn = 0; kn < 4; ++kn) {
        float pv = exp2f(p[kn][r] - nm);
        p[kn][r] = pv;
        rs += pv;
      }
      l_run[r] = l_run[r] * fac[r] + rs;
    }
#pragma unroll
    for (int dn = 0; dn < 4; ++dn) {
      f32x4 o = oacc[dn];
      o[0] *= fac[0]; o[1] *= fac[1]; o[2] *= fac[2]; o[3] *= fac[3];
      oacc[dn] = o;
    }

    short* myP = &Ps[wid][0];
#pragma unroll
    for (int r = 0; r < 4; ++r)
#pragma unroll
      for (int kn = 0; kn < 4; ++kn)
        myP[(((l >> 4) << 2) + r) * 72 + kn*16 + (l & 15)] = (short)f2bf(p[kn][r]);

#pragma unroll
    for (int kk = 0; kk < 2; ++kk) {
      short8_t pf = *(const short8_t*)((const char*)myP + (l & 15)*144 + kk*64 + (l >> 4)*16);
#pragma unroll
      for (int dn = 0; dn < 4; ++dn) {
        int row = dn*16 + (l & 15);
        int slot = (kk*4 + (l >> 4)) ^ (row & 7);
        short8_t vf = *(const short8_t*)((const char*)Vs + row*128 + slot*16);
        oacc[dn] = __builtin_amdgcn_mfma_f32_16x16x32_bf16(pf, vf, oacc[dn], 0, 0, 0);
      }
    }
  }

  float linv[4];
#pragma unroll
  for (int r = 0; r < 4; ++r) {
    float s = l_run[r];
#pragma unroll
    for (int d = 1; d < 16; d <<= 1) s += __shfl_xor(s, d);
    linv[r] = 1.f / s;
  }
  int orow = qt*64 + wid*16 + ((l >> 4) << 2);
#pragma unroll
  for (int dn = 0; dn < 4; ++dn)
#pragma unroll
    for (int r = 0; r < 4; ++r) {
      float v = oacc[dn][r] * linv[r];
      size_t off = ((size_t)b * S_ + orow + r) * C_ + h*64 + dn*16 + (l & 15);
      outp[off] = f2bf(v);
    }
}

// ---------------- launcher ----------------
extern "C" void kernel_launch(void* const* d_in, const int* in_sizes, int n_in,
                              void* d_out, int out_size, void* d_ws, size_t ws_size,
                              hipStream_t stream) {
  const float* hs = (const float*)d_in[0];
  const int*   msk = (const int*)d_in[1];
  const float* gw = (const float*)d_in[2];
  const float* gb = (const float*)d_in[3];
  const float* Wq = (const float*)d_in[4];
  const float* bq = (const float*)d_in[5];
  const float* Wk = (const float*)d_in[6];
  const float* bk = (const float*)d_in[7];
  const float* Wv = (const float*)d_in[8];
  const float* bv = (const float*)d_in[9];
  const float* Wo = (const float*)d_in[10];
  const float* bo = (const float*)d_in[11];

  char* ws = (char*)d_ws;
  float*  stats = (float*)(ws);
  float2* part  = (float2*)(ws + 256);
  unsigned short* wq_b = (unsigned short*)(ws + 8192);
  unsigned short* wk_b = wq_b + 1048576;
  unsigned short* wv_b = wk_b + 1048576;
  unsigned short* wo_b = wv_b + 1048576;
  unsigned short* x_b  = wo_b + 1048576;     // (B,S,C) bf16
  unsigned short* q_b  = x_b  + 4194304;     // (B,H,S,D)
  unsigned short* k_b  = q_b  + 4194304;     // (B,H,S,D)
  unsigned short* vt_b = k_b  + 4194304;     // (B,H,D,S)
  unsigned short* ao_b = vt_b + 4194304;     // (B,S,C)

  cvt_w<<<1024, 256, 0, stream>>>(Wq, wq_b);
  cvt_w<<<1024, 256, 0, stream>>>(Wk, wk_b);
  cvt_w<<<1024, 256, 0, stream>>>(Wv, wv_b);
  cvt_w<<<1024, 256, 0, stream>>>(Wo, wo_b);

  stats1<<<512, 256, 0, stream>>>(hs, part);
  stats2<<<2, 256, 0, stream>>>(part, stats);
  normt<<<1024, 256, 0, stream>>>(hs, gw, gb, stats, x_b);

  gemm_nt<0><<<512, 256, 0, stream>>>(x_b, wq_b, bq, nullptr, q_b, 8);
  gemm_nt<0><<<512, 256, 0, stream>>>(x_b, wk_b, bk, nullptr, k_b, 8);
  gemm_nt<1><<<512, 256, 0, stream>>>(wv_b, x_b, bv, nullptr, vt_b, 32);

  attn_kernel<<<1024, 256, 0, stream>>>(q_b, k_b, vt_b, msk, ao_b);

  gemm_nt<2><<<512, 256, 0, stream>>>(wo_b, ao_b, bo, hs, d_out, 32);
}

// Round 2
// 152.225 us; speedup vs baseline: 1.2893x; 1.2893x over previous
//
#include <hip/hip_runtime.h>
#include <hip/hip_bf16.h>

#define B_ 2
#define C_ 1024
#define S_ 2048
#define H_ 16
#define KDIM 1024

typedef __attribute__((ext_vector_type(8))) short short8_t;
typedef __attribute__((ext_vector_type(4))) float f32x4;
typedef __attribute__((ext_vector_type(16))) float f32x16;
typedef __attribute__((ext_vector_type(4))) int i32x4;

__device__ __forceinline__ void glds16(const void* g, void* l) {
  __builtin_amdgcn_global_load_lds((const __attribute__((address_space(1))) void*)g,
                                   (__attribute__((address_space(3))) void*)l, 16, 0, 0);
}

__device__ __forceinline__ unsigned short f2bf(float f) {
  __hip_bfloat16 h = __float2bfloat16(f);
  return __builtin_bit_cast(unsigned short, h);
}

__device__ __forceinline__ unsigned pkbf(float lo, float hi) {
  unsigned r;
  asm("v_cvt_pk_bf16_f32 %0, %1, %2" : "=v"(r) : "v"(lo), "v"(hi));
  return r;
}

__device__ __forceinline__ void plswap(unsigned &a, unsigned &b) {
  asm("v_permlane32_swap_b32 %0, %1" : "+v"(a), "+v"(b));
}

// ---------------- weight fp32 -> bf16 ----------------
__global__ __launch_bounds__(256) void cvt_w(const float* __restrict__ w,
                                             unsigned short* __restrict__ o) {
  int i = blockIdx.x * 256 + threadIdx.x;           // 262144 float4s
  float4 v = ((const float4*)w)[i];
  short4 r;
  r.x = (short)f2bf(v.x); r.y = (short)f2bf(v.y);
  r.z = (short)f2bf(v.z); r.w = (short)f2bf(v.w);
  ((short4*)o)[i] = r;
}

// ---------------- per-batch stats (two-stage, deterministic) ----------------
__global__ __launch_bounds__(256) void stats1(const float* __restrict__ x,
                                              float2* __restrict__ part) {
  int bid = blockIdx.x;                             // 512 blocks
  int b = bid >> 8, chunk = bid & 255;
  const float4* p = (const float4*)(x + (size_t)b*(C_*S_) + (size_t)chunk*8192);
  int t = threadIdx.x;
  float s = 0.f, q = 0.f;
#pragma unroll
  for (int i = 0; i < 8; ++i) {
    float4 v = p[t + i*256];
    s += v.x + v.y + v.z + v.w;
    q += v.x*v.x + v.y*v.y + v.z*v.z + v.w*v.w;
  }
#pragma unroll
  for (int d = 1; d < 64; d <<= 1) { s += __shfl_xor(s, d); q += __shfl_xor(q, d); }
  __shared__ float2 wsum[4];
  if ((t & 63) == 0) wsum[t >> 6] = make_float2(s, q);
  __syncthreads();
  if (t == 0) {
    float S = 0.f, Q = 0.f;
    for (int i = 0; i < 4; ++i) { S += wsum[i].x; Q += wsum[i].y; }
    part[bid] = make_float2(S, Q);
  }
}

__global__ __launch_bounds__(256) void stats2(const float2* __restrict__ part,
                                              float* __restrict__ stats) {
  int b = blockIdx.x;
  int t = threadIdx.x;
  float2 v = part[b*256 + t];
  float s = v.x, q = v.y;
#pragma unroll
  for (int d = 1; d < 64; d <<= 1) { s += __shfl_xor(s, d); q += __shfl_xor(q, d); }
  __shared__ float2 wsum[4];
  if ((t & 63) == 0) wsum[t >> 6] = make_float2(s, q);
  __syncthreads();
  if (t == 0) {
    float S = 0.f, Q = 0.f;
    for (int i = 0; i < 4; ++i) { S += wsum[i].x; Q += wsum[i].y; }
    const float invN = 1.0f / (float)(C_*S_);
    float mean = S * invN;
    float var = Q * invN - mean*mean;
    stats[b*2]   = mean;
    stats[b*2+1] = rsqrtf(var + 1e-5f);
  }
}

// ---------------- normalize + transpose (B,C,S)f32 -> (B,S,C)bf16 ----------------
__global__ __launch_bounds__(256) void normt(const float* __restrict__ x,
                                             const float* __restrict__ gw,
                                             const float* __restrict__ gb,
                                             const float* __restrict__ stats,
                                             unsigned short* __restrict__ xt) {
  __shared__ short lds[64*72];
  int bid = blockIdx.x;                              // 1024 blocks
  int b = bid >> 9, rem = bid & 511;
  int ct = rem >> 5, st = rem & 31;
  float mean = stats[b*2], rstd = stats[b*2+1];
  int t = threadIdx.x;
  int r = t >> 2, seg = t & 3;
  int c = ct*64 + r;
  float wsc = gw[c] * rstd;
  float bof = gb[c] - mean * wsc;
  const float4* src = (const float4*)(x + (size_t)b*(C_*S_) + (size_t)c*S_ + st*64 + seg*16);
#pragma unroll
  for (int j = 0; j < 4; ++j) {
    float4 v = src[j];
    int sl = seg*16 + j*4;
    lds[(sl+0)*72 + r] = (short)f2bf(v.x*wsc + bof);
    lds[(sl+1)*72 + r] = (short)f2bf(v.y*wsc + bof);
    lds[(sl+2)*72 + r] = (short)f2bf(v.z*wsc + bof);
    lds[(sl+3)*72 + r] = (short)f2bf(v.w*wsc + bof);
  }
  __syncthreads();
  int sl = t >> 2;
  __attribute__((aligned(16))) unsigned short tmp[16];
#pragma unroll
  for (int j = 0; j < 16; ++j) tmp[j] = (unsigned short)lds[sl*72 + seg*16 + j];
  unsigned short* dst = xt + ((size_t)b*S_ + st*64 + sl) * C_ + ct*64 + seg*16;
  *(short8_t*)dst       = *(const short8_t*)tmp;
  *(short8_t*)(dst + 8) = *(const short8_t*)(tmp + 8);
}

// ---------------- NT GEMM: C[m,n] = sum_k A[m,k]*B[n,k] (K=1024) ----------------
template<int EPI>
__global__ __launch_bounds__(256)
void gemm_nt(const unsigned short* __restrict__ A,
             const unsigned short* __restrict__ Bm,
             const float* __restrict__ bias,
             const float* __restrict__ resid,
             void* __restrict__ outp,
             int nbn) {
  __shared__ __attribute__((aligned(16))) short As[64*64];
  __shared__ __attribute__((aligned(16))) short Bs[128*64];
  int nwg = gridDim.x;
  int bid = blockIdx.x;
  int cpx = nwg >> 3;                                // grid % 8 == 0
  int sbid = (bid & 7) * cpx + (bid >> 3);
  int bm = sbid / nbn, bn = sbid % nbn;
  int m0 = bm << 6, n0 = bn << 7;
  int t = threadIdx.x;
  int l = t & 63, wid = t >> 6;

  int r_st = t >> 3;                                 // 0..31
  int slot_src = (t & 7) ^ (r_st & 7);               // pre-swizzled source slot
  const unsigned short* a_src = A + (size_t)(m0 + r_st) * KDIM + slot_src * 8;
  const unsigned short* b_src = Bm + (size_t)(n0 + r_st) * KDIM + slot_src * 8;
  char* As_base = (char*)As + wid*1024;
  char* Bs_base = (char*)Bs + wid*1024;

  f32x4 acc[4][2] = {};

  for (int kt = 0; kt < KDIM; kt += 64) {
    __syncthreads();
    glds16(a_src + kt, As_base);
    glds16(a_src + (size_t)32*KDIM + kt, As_base + 4096);
#pragma unroll
    for (int i = 0; i < 4; ++i)
      glds16(b_src + (size_t)(i*32)*KDIM + kt, Bs_base + i*4096);
    __syncthreads();
#pragma unroll
    for (int kk = 0; kk < 2; ++kk) {
      short8_t af[4], bfr[2];
#pragma unroll
      for (int mi = 0; mi < 4; ++mi) {
        int row = mi*16 + (l & 15);
        int slot = (kk*4 + (l >> 4)) ^ (row & 7);
        af[mi] = *(const short8_t*)((const char*)As + row*128 + slot*16);
      }
#pragma unroll
      for (int ni = 0; ni < 2; ++ni) {
        int row = wid*32 + ni*16 + (l & 15);
        int slot = (kk*4 + (l >> 4)) ^ (row & 7);
        bfr[ni] = *(const short8_t*)((const char*)Bs + row*128 + slot*16);
      }
#pragma unroll
      for (int mi = 0; mi < 4; ++mi)
#pragma unroll
        for (int ni = 0; ni < 2; ++ni)
          acc[mi][ni] = __builtin_amdgcn_mfma_f32_16x16x32_bf16(af[mi], bfr[ni], acc[mi][ni], 0, 0, 0);
    }
  }

#pragma unroll
  for (int mi = 0; mi < 4; ++mi) {
#pragma unroll
    for (int ni = 0; ni < 2; ++ni) {
#pragma unroll
      for (int r = 0; r < 4; ++r) {
        int gm = m0 + mi*16 + ((l >> 4) << 2) + r;
        int gn = n0 + wid*32 + ni*16 + (l & 15);
        float v = acc[mi][ni][r];
        if (EPI == 0) {
          v += bias[gn];
          size_t off = ((size_t)((gm >> 11)*H_ + (gn >> 6)) * S_ + (gm & 2047)) * 64 + (gn & 63);
          ((unsigned short*)outp)[off] = f2bf(v);
        } else {
          v += bias[gm];
          size_t off = (size_t)(gn >> 11) * ((size_t)C_*S_) + (size_t)gm * S_ + (gn & 2047);
          if (EPI == 1) {
            ((unsigned short*)outp)[off] = f2bf(v);
          } else {
            ((float*)outp)[off] = v + resid[off];
          }
        }
      }
    }
  }
}

// ---------------- flash attention, swapped 32x32 (S^T / O^T in-register) -------
// Q,K: (B,H,S,D) bf16; Vt: (B,H,D,S) bf16; out ao: (B,S,C) bf16
// 2 waves/block, each wave: 32 q-rows, KVBLK=64, softmax fully in-register.
__global__ __launch_bounds__(128)
void attn_kernel(const unsigned short* __restrict__ Q,
                 const unsigned short* __restrict__ Kt,
                 const unsigned short* __restrict__ Vt,
                 const int* __restrict__ mask,
                 unsigned short* __restrict__ outp) {
  __shared__ __attribute__((aligned(16))) short Ks[64*64];   // [k][d] swizzled
  __shared__ __attribute__((aligned(16))) short Vs[64*64];   // [d][k] swizzled
  __shared__ __attribute__((aligned(8)))  unsigned char maskb[256];
  __shared__ int tflag[32];

  int bid = blockIdx.x;                              // 1024 blocks
  int bid2 = (bid & 7) * 128 + (bid >> 3);           // XCD swizzle (bijective)
  int bh = bid2 >> 5, qt = bid2 & 31;
  int b = bh >> 4, h = bh & 15;
  int t = threadIdx.x, l = t & 63, wid = t >> 6;
  int hh = l >> 5;                                   // half-lane index

  // ---- mask prologue: bit-pack + per-64-tile all-ones flags ----
  {
    const i32x4* mp = (const i32x4*)(mask + b * S_) + t * 4;
    i32x4 m0 = mp[0], m1 = mp[1], m2 = mp[2], m3 = mp[3];
    unsigned by0 = (unsigned)(m0[0]!=0) | ((unsigned)(m0[1]!=0)<<1) | ((unsigned)(m0[2]!=0)<<2) | ((unsigned)(m0[3]!=0)<<3)
                 | ((unsigned)(m1[0]!=0)<<4) | ((unsigned)(m1[1]!=0)<<5) | ((unsigned)(m1[2]!=0)<<6) | ((unsigned)(m1[3]!=0)<<7);
    unsigned by1 = (unsigned)(m2[0]!=0) | ((unsigned)(m2[1]!=0)<<1) | ((unsigned)(m2[2]!=0)<<2) | ((unsigned)(m2[3]!=0)<<3)
                 | ((unsigned)(m3[0]!=0)<<4) | ((unsigned)(m3[1]!=0)<<5) | ((unsigned)(m3[2]!=0)<<6) | ((unsigned)(m3[3]!=0)<<7);
    maskb[2*t]   = (unsigned char)by0;
    maskb[2*t+1] = (unsigned char)by1;
  }
  __syncthreads();
  if (t < 32) {
    unsigned long long v = ((const unsigned long long*)maskb)[t];
    tflag[t] = (v == 0xFFFFFFFFFFFFFFFFull) ? 1 : 0;
  }

  // ---- Q fragments (B-operand): q-col = l&31, d = 16c + 8hh + j ----
  int q0 = qt*64 + wid*32;
  const unsigned short* qp = Q + ((size_t)bh * S_ + q0 + (l & 31)) * 64 + hh * 8;
  short8_t qf[4];
#pragma unroll
  for (int c = 0; c < 4; ++c) qf[c] = *(const short8_t*)(qp + c*16);

  // ---- staging pointers (pre-swizzled source, linear LDS dest) ----
  const unsigned short* ksrc = Kt + ((size_t)bh * S_ + wid*8 + (l >> 3)) * 64 + ((l & 7) ^ (l >> 3)) * 8;
  const unsigned short* vsrc = Vt + ((size_t)bh * 64 + wid*8 + (l >> 3)) * S_ + ((l & 7) ^ (l >> 3)) * 8;
  char* Ksb = (char*)Ks + wid*1024;
  char* Vsb = (char*)Vs + wid*1024;

  const float SC = 0.18033688011112042f;             // (1/8) * log2(e)
  float m_run = -1e30f, l_run = 0.f;
  f32x16 oc0 = {}, oc1 = {};

  for (int kt0 = 0; kt0 < S_; kt0 += 64) {
    __syncthreads();
#pragma unroll
    for (int i = 0; i < 4; ++i) {
      glds16(ksrc + (size_t)(kt0 + i*16) * 64, Ksb + i*2048);
      glds16(vsrc + (size_t)(i*16) * S_ + kt0, Vsb + i*2048);
    }
    __syncthreads();
    int allone = tflag[kt0 >> 6];

    // ---- QK^T (swapped): st[tile] = K_tile . Q^T, lane holds q=l&31 ----
    f32x16 st0 = {}, st1 = {};
#pragma unroll
    for (int c = 0; c < 4; ++c) {
      int row0 = (l & 31);
      int slot = (c*2 + hh) ^ (l & 7);
      short8_t kf0 = *(const short8_t*)((const char*)Ks + row0*128 + slot*16);
      short8_t kf1 = *(const short8_t*)((const char*)Ks + (row0+32)*128 + slot*16);
      st0 = __builtin_amdgcn_mfma_f32_32x32x16_bf16(kf0, qf[c], st0, 0, 0, 0);
      st1 = __builtin_amdgcn_mfma_f32_32x32x16_bf16(kf1, qf[c], st1, 0, 0, 0);
    }

    // ---- in-register online softmax (log2 domain) ----
    float mx = st0[0];
#pragma unroll
    for (int r = 1; r < 16; ++r) mx = fmaxf(mx, st0[r]);
#pragma unroll
    for (int r = 0; r < 16; ++r) mx = fmaxf(mx, st1[r]);
    mx = fmaxf(mx, __shfl_xor(mx, 32));
    float nm = fmaxf(m_run, mx);
    float fac = __builtin_amdgcn_exp2f((m_run - nm) * SC);
    m_run = nm;
    float nms = nm * SC;

    float p0[16], p1[16];
#pragma unroll
    for (int r = 0; r < 16; ++r) {
      p0[r] = __builtin_amdgcn_exp2f(st0[r]*SC - nms);
      p1[r] = __builtin_amdgcn_exp2f(st1[r]*SC - nms);
    }
    if (!allone) {                                   // rare path: zero masked p
#pragma unroll
      for (int r = 0; r < 16; ++r) {
        int kl = kt0 + (r & 3) + 8*(r >> 2) + 4*hh;
        if (!((maskb[kl >> 3] >> (kl & 7)) & 1)) p0[r] = 0.f;
        kl += 32;
        if (!((maskb[kl >> 3] >> (kl & 7)) & 1)) p1[r] = 0.f;
      }
    }
    float ss = 0.f;
#pragma unroll
    for (int r = 0; r < 16; ++r) ss += p0[r] + p1[r];
    l_run = l_run * fac + ss;
#pragma unroll
    for (int r = 0; r < 16; ++r) { oc0[r] *= fac; oc1[r] *= fac; }

    // ---- repack P -> bf16 B-operand fragments via cvt_pk + permlane32_swap ----
    short8_t pa[4];
    {
      unsigned a0 = pkbf(p0[0],  p0[1]),  b0 = pkbf(p0[4],  p0[5]);
      unsigned a1 = pkbf(p0[2],  p0[3]),  b1 = pkbf(p0[6],  p0[7]);
      plswap(a0, b0); plswap(a1, b1);
      i32x4 w0 = {(int)a0, (int)a1, (int)b0, (int)b1};
      pa[0] = __builtin_bit_cast(short8_t, w0);
      unsigned a2 = pkbf(p0[8],  p0[9]),  b2 = pkbf(p0[12], p0[13]);
      unsigned a3 = pkbf(p0[10], p0[11]), b3 = pkbf(p0[14], p0[15]);
      plswap(a2, b2); plswap(a3, b3);
      i32x4 w1 = {(int)a2, (int)a3, (int)b2, (int)b3};
      pa[1] = __builtin_bit_cast(short8_t, w1);
      unsigned a4 = pkbf(p1[0],  p1[1]),  b4 = pkbf(p1[4],  p1[5]);
      unsigned a5 = pkbf(p1[2],  p1[3]),  b5 = pkbf(p1[6],  p1[7]);
      plswap(a4, b4); plswap(a5, b5);
      i32x4 w2 = {(int)a4, (int)a5, (int)b4, (int)b5};
      pa[2] = __builtin_bit_cast(short8_t, w2);
      unsigned a6 = pkbf(p1[8],  p1[9]),  b6 = pkbf(p1[12], p1[13]);
      unsigned a7 = pkbf(p1[10], p1[11]), b7 = pkbf(p1[14], p1[15]);
      plswap(a6, b6); plswap(a7, b7);
      i32x4 w3 = {(int)a6, (int)a7, (int)b6, (int)b7};
      pa[3] = __builtin_bit_cast(short8_t, w3);
    }

    // ---- PV (swapped): O^T += V^T . P^T ----
#pragma unroll
    for (int kc = 0; kc < 4; ++kc) {
      int row0 = (l & 31);
      int slot = (kc*2 + hh) ^ (l & 7);
      short8_t vf0 = *(const short8_t*)((const char*)Vs + row0*128 + slot*16);
      short8_t vf1 = *(const short8_t*)((const char*)Vs + (row0+32)*128 + slot*16);
      oc0 = __builtin_amdgcn_mfma_f32_32x32x16_bf16(vf0, pa[kc], oc0, 0, 0, 0);
      oc1 = __builtin_amdgcn_mfma_f32_32x32x16_bf16(vf1, pa[kc], oc1, 0, 0, 0);
    }
  }

  // ---- epilogue: normalize, pack, store ----
  float ltot = l_run + __shfl_xor(l_run, 32);
  float inv = 1.f / ltot;
#pragma unroll
  for (int r = 0; r < 16; ++r) { oc0[r] *= inv; oc1[r] *= inv; }

  unsigned short* obase = outp + ((size_t)b * S_ + q0 + (l & 31)) * C_ + h*64 + hh*8;
#pragma unroll
  for (int dt = 0; dt < 2; ++dt) {
    const f32x16& oc = dt ? oc1 : oc0;
    unsigned a0 = pkbf(oc[0],  oc[1]),  b0 = pkbf(oc[4],  oc[5]);
    unsigned a1 = pkbf(oc[2],  oc[3]),  b1 = pkbf(oc[6],  oc[7]);
    plswap(a0, b0); plswap(a1, b1);
    i32x4 w0 = {(int)a0, (int)a1, (int)b0, (int)b1};
    *(i32x4*)(obase + dt*32) = w0;
    unsigned a2 = pkbf(oc[8],  oc[9]),  b2 = pkbf(oc[12], oc[13]);
    unsigned a3 = pkbf(oc[10], oc[11]), b3 = pkbf(oc[14], oc[15]);
    plswap(a2, b2); plswap(a3, b3);
    i32x4 w1 = {(int)a2, (int)a3, (int)b2, (int)b3};
    *(i32x4*)(obase + dt*32 + 16) = w1;
  }
}

// ---------------- launcher ----------------
extern "C" void kernel_launch(void* const* d_in, const int* in_sizes, int n_in,
                              void* d_out, int out_size, void* d_ws, size_t ws_size,
                              hipStream_t stream) {
  const float* hs = (const float*)d_in[0];
  const int*   msk = (const int*)d_in[1];
  const float* gw = (const float*)d_in[2];
  const float* gb = (const float*)d_in[3];
  const float* Wq = (const float*)d_in[4];
  const float* bq = (const float*)d_in[5];
  const float* Wk = (const float*)d_in[6];
  const float* bk = (const float*)d_in[7];
  const float* Wv = (const float*)d_in[8];
  const float* bv = (const float*)d_in[9];
  const float* Wo = (const float*)d_in[10];
  const float* bo = (const float*)d_in[11];

  char* ws = (char*)d_ws;
  float*  stats = (float*)(ws);
  float2* part  = (float2*)(ws + 256);
  unsigned short* wq_b = (unsigned short*)(ws + 8192);
  unsigned short* wk_b = wq_b + 1048576;
  unsigned short* wv_b = wk_b + 1048576;
  unsigned short* wo_b = wv_b + 1048576;
  unsigned short* x_b  = wo_b + 1048576;     // (B,S,C) bf16
  unsigned short* q_b  = x_b  + 4194304;     // (B,H,S,D)
  unsigned short* k_b  = q_b  + 4194304;     // (B,H,S,D)
  unsigned short* vt_b = k_b  + 4194304;     // (B,H,D,S)
  unsigned short* ao_b = vt_b + 4194304;     // (B,S,C)

  cvt_w<<<1024, 256, 0, stream>>>(Wq, wq_b);
  cvt_w<<<1024, 256, 0, stream>>>(Wk, wk_b);
  cvt_w<<<1024, 256, 0, stream>>>(Wv, wv_b);
  cvt_w<<<1024, 256, 0, stream>>>(Wo, wo_b);

  stats1<<<512, 256, 0, stream>>>(hs, part);
  stats2<<<2, 256, 0, stream>>>(part, stats);
  normt<<<1024, 256, 0, stream>>>(hs, gw, gb, stats, x_b);

  gemm_nt<0><<<512, 256, 0, stream>>>(x_b, wq_b, bq, nullptr, q_b, 8);
  gemm_nt<0><<<512, 256, 0, stream>>>(x_b, wk_b, bk, nullptr, k_b, 8);
  gemm_nt<1><<<512, 256, 0, stream>>>(wv_b, x_b, bv, nullptr, vt_b, 32);

  attn_kernel<<<1024, 128, 0, stream>>>(q_b, k_b, vt_b, msk, ao_b);

  gemm_nt<2><<<512, 256, 0, stream>>>(wo_b, ao_b, bo, hs, d_out, 32);
}

// Round 3
// 146.246 us; speedup vs baseline: 1.3420x; 1.0409x over previous
//
#include <hip/hip_runtime.h>
#include <hip/hip_bf16.h>

#define B_ 2
#define C_ 1024
#define S_ 2048
#define H_ 16
#define KDIM 1024

typedef __attribute__((ext_vector_type(8))) short short8_t;
typedef __attribute__((ext_vector_type(4))) float f32x4;
typedef __attribute__((ext_vector_type(16))) float f32x16;
typedef __attribute__((ext_vector_type(4))) int i32x4;

__device__ __forceinline__ void glds16(const void* g, void* l) {
  __builtin_amdgcn_global_load_lds((const __attribute__((address_space(1))) void*)g,
                                   (__attribute__((address_space(3))) void*)l, 16, 0, 0);
}

__device__ __forceinline__ unsigned short f2bf(float f) {
  __hip_bfloat16 h = __float2bfloat16(f);
  return __builtin_bit_cast(unsigned short, h);
}

__device__ __forceinline__ unsigned pkbf(float lo, float hi) {
  unsigned r;
  asm("v_cvt_pk_bf16_f32 %0, %1, %2" : "=v"(r) : "v"(lo), "v"(hi));
  return r;
}

__device__ __forceinline__ void plswap(unsigned &a, unsigned &b) {
  asm("v_permlane32_swap_b32 %0, %1" : "+v"(a), "+v"(b));
}

__device__ __forceinline__ float max16f(const f32x16& v) {
  float a = fmaxf(fmaxf(v[0], v[1]),  fmaxf(v[2], v[3]));
  float b = fmaxf(fmaxf(v[4], v[5]),  fmaxf(v[6], v[7]));
  float c = fmaxf(fmaxf(v[8], v[9]),  fmaxf(v[10], v[11]));
  float d = fmaxf(fmaxf(v[12], v[13]), fmaxf(v[14], v[15]));
  return fmaxf(fmaxf(a, b), fmaxf(c, d));
}

__device__ __forceinline__ float sum16f(const float* p) {
  float a = (p[0] + p[1]) + (p[2] + p[3]);
  float b = (p[4] + p[5]) + (p[6] + p[7]);
  float c = (p[8] + p[9]) + (p[10] + p[11]);
  float d = (p[12] + p[13]) + (p[14] + p[15]);
  return (a + b) + (c + d);
}

// ---------------- weight fp32 -> bf16 (all 4 in one launch) ----------------
__global__ __launch_bounds__(256) void cvt_w4(const float* __restrict__ a,
                                              const float* __restrict__ b,
                                              const float* __restrict__ c,
                                              const float* __restrict__ d,
                                              unsigned short* __restrict__ o) {
  int g = blockIdx.x >> 10;
  const float* src = (g == 0) ? a : (g == 1) ? b : (g == 2) ? c : d;
  int i = (blockIdx.x & 1023) * 256 + threadIdx.x;
  float4 v = ((const float4*)src)[i];
  short4 r;
  r.x = (short)f2bf(v.x); r.y = (short)f2bf(v.y);
  r.z = (short)f2bf(v.z); r.w = (short)f2bf(v.w);
  ((short4*)(o))[(size_t)g * 262144 + i] = r;
}

// ---------------- per-batch stats (two-stage, deterministic) ----------------
__global__ __launch_bounds__(256) void stats1(const float* __restrict__ x,
                                              float2* __restrict__ part) {
  int bid = blockIdx.x;                             // 512 blocks
  int b = bid >> 8, chunk = bid & 255;
  const float4* p = (const float4*)(x + (size_t)b*(C_*S_) + (size_t)chunk*8192);
  int t = threadIdx.x;
  float s = 0.f, q = 0.f;
#pragma unroll
  for (int i = 0; i < 8; ++i) {
    float4 v = p[t + i*256];
    s += v.x + v.y + v.z + v.w;
    q += v.x*v.x + v.y*v.y + v.z*v.z + v.w*v.w;
  }
#pragma unroll
  for (int d = 1; d < 64; d <<= 1) { s += __shfl_xor(s, d); q += __shfl_xor(q, d); }
  __shared__ float2 wsum[4];
  if ((t & 63) == 0) wsum[t >> 6] = make_float2(s, q);
  __syncthreads();
  if (t == 0) {
    float S = 0.f, Q = 0.f;
    for (int i = 0; i < 4; ++i) { S += wsum[i].x; Q += wsum[i].y; }
    part[bid] = make_float2(S, Q);
  }
}

__global__ __launch_bounds__(256) void stats2(const float2* __restrict__ part,
                                              float* __restrict__ stats) {
  int b = blockIdx.x;
  int t = threadIdx.x;
  float2 v = part[b*256 + t];
  float s = v.x, q = v.y;
#pragma unroll
  for (int d = 1; d < 64; d <<= 1) { s += __shfl_xor(s, d); q += __shfl_xor(q, d); }
  __shared__ float2 wsum[4];
  if ((t & 63) == 0) wsum[t >> 6] = make_float2(s, q);
  __syncthreads();
  if (t == 0) {
    float S = 0.f, Q = 0.f;
    for (int i = 0; i < 4; ++i) { S += wsum[i].x; Q += wsum[i].y; }
    const float invN = 1.0f / (float)(C_*S_);
    float mean = S * invN;
    float var = Q * invN - mean*mean;
    stats[b*2]   = mean;
    stats[b*2+1] = rsqrtf(var + 1e-5f);
  }
}

// ---------------- normalize + transpose (B,C,S)f32 -> (B,S,C)bf16 ----------------
__global__ __launch_bounds__(256) void normt(const float* __restrict__ x,
                                             const float* __restrict__ gw,
                                             const float* __restrict__ gb,
                                             const float* __restrict__ stats,
                                             unsigned short* __restrict__ xt) {
  __shared__ short lds[64*72];
  int bid = blockIdx.x;                              // 1024 blocks
  int b = bid >> 9, rem = bid & 511;
  int ct = rem >> 5, st = rem & 31;
  float mean = stats[b*2], rstd = stats[b*2+1];
  int t = threadIdx.x;
  int r = t >> 2, seg = t & 3;
  int c = ct*64 + r;
  float wsc = gw[c] * rstd;
  float bof = gb[c] - mean * wsc;
  const float4* src = (const float4*)(x + (size_t)b*(C_*S_) + (size_t)c*S_ + st*64 + seg*16);
#pragma unroll
  for (int j = 0; j < 4; ++j) {
    float4 v = src[j];
    int sl = seg*16 + j*4;
    lds[(sl+0)*72 + r] = (short)f2bf(v.x*wsc + bof);
    lds[(sl+1)*72 + r] = (short)f2bf(v.y*wsc + bof);
    lds[(sl+2)*72 + r] = (short)f2bf(v.z*wsc + bof);
    lds[(sl+3)*72 + r] = (short)f2bf(v.w*wsc + bof);
  }
  __syncthreads();
  int sl = t >> 2;
  __attribute__((aligned(16))) unsigned short tmp[16];
#pragma unroll
  for (int j = 0; j < 16; ++j) tmp[j] = (unsigned short)lds[sl*72 + seg*16 + j];
  unsigned short* dst = xt + ((size_t)b*S_ + st*64 + sl) * C_ + ct*64 + seg*16;
  *(short8_t*)dst       = *(const short8_t*)tmp;
  *(short8_t*)(dst + 8) = *(const short8_t*)(tmp + 8);
}

// ---------------- NT GEMM: C[m,n] = sum_k A[m,k]*B[n,k] (K=1024) ----------------
template<int EPI>
__global__ __launch_bounds__(256)
void gemm_nt(const unsigned short* __restrict__ A,
             const unsigned short* __restrict__ Bm,
             const float* __restrict__ bias,
             const float* __restrict__ resid,
             void* __restrict__ outp,
             int nbn) {
  __shared__ __attribute__((aligned(16))) short As[64*64];
  __shared__ __attribute__((aligned(16))) short Bs[128*64];
  int nwg = gridDim.x;
  int bid = blockIdx.x;
  int cpx = nwg >> 3;                                // grid % 8 == 0
  int sbid = (bid & 7) * cpx + (bid >> 3);
  int bm = sbid / nbn, bn = sbid % nbn;
  int m0 = bm << 6, n0 = bn << 7;
  int t = threadIdx.x;
  int l = t & 63, wid = t >> 6;

  int r_st = t >> 3;                                 // 0..31
  int slot_src = (t & 7) ^ (r_st & 7);               // pre-swizzled source slot
  const unsigned short* a_src = A + (size_t)(m0 + r_st) * KDIM + slot_src * 8;
  const unsigned short* b_src = Bm + (size_t)(n0 + r_st) * KDIM + slot_src * 8;
  char* As_base = (char*)As + wid*1024;
  char* Bs_base = (char*)Bs + wid*1024;

  f32x4 acc[4][2] = {};

  for (int kt = 0; kt < KDIM; kt += 64) {
    __syncthreads();
    glds16(a_src + kt, As_base);
    glds16(a_src + (size_t)32*KDIM + kt, As_base + 4096);
#pragma unroll
    for (int i = 0; i < 4; ++i)
      glds16(b_src + (size_t)(i*32)*KDIM + kt, Bs_base + i*4096);
    __syncthreads();
#pragma unroll
    for (int kk = 0; kk < 2; ++kk) {
      short8_t af[4], bfr[2];
#pragma unroll
      for (int mi = 0; mi < 4; ++mi) {
        int row = mi*16 + (l & 15);
        int slot = (kk*4 + (l >> 4)) ^ (row & 7);
        af[mi] = *(const short8_t*)((const char*)As + row*128 + slot*16);
      }
#pragma unroll
      for (int ni = 0; ni < 2; ++ni) {
        int row = wid*32 + ni*16 + (l & 15);
        int slot = (kk*4 + (l >> 4)) ^ (row & 7);
        bfr[ni] = *(const short8_t*)((const char*)Bs + row*128 + slot*16);
      }
#pragma unroll
      for (int mi = 0; mi < 4; ++mi)
#pragma unroll
        for (int ni = 0; ni < 2; ++ni)
          acc[mi][ni] = __builtin_amdgcn_mfma_f32_16x16x32_bf16(af[mi], bfr[ni], acc[mi][ni], 0, 0, 0);
    }
  }

#pragma unroll
  for (int mi = 0; mi < 4; ++mi) {
#pragma unroll
    for (int ni = 0; ni < 2; ++ni) {
#pragma unroll
      for (int r = 0; r < 4; ++r) {
        int gm = m0 + mi*16 + ((l >> 4) << 2) + r;
        int gn = n0 + wid*32 + ni*16 + (l & 15);
        float v = acc[mi][ni][r];
        if (EPI == 0) {
          v += bias[gn];
          size_t off = ((size_t)((gm >> 11)*H_ + (gn >> 6)) * S_ + (gm & 2047)) * 64 + (gn & 63);
          ((unsigned short*)outp)[off] = f2bf(v);
        } else {
          v += bias[gm];
          size_t off = (size_t)(gn >> 11) * ((size_t)C_*S_) + (size_t)gm * S_ + (gn & 2047);
          if (EPI == 1) {
            ((unsigned short*)outp)[off] = f2bf(v);
          } else {
            ((float*)outp)[off] = v + resid[off];
          }
        }
      }
    }
  }
}

// ---------------- flash attention, swapped 32x32, dbuf + speculative exp ------
// Q,K: (B,H,S,D) bf16; Vt: (B,H,D,S) bf16; out ao: (B,S,C) bf16
// 4 waves/block, 32 q-rows/wave (128/block), KVBLK=64, double-buffered K/V LDS.
__global__ __launch_bounds__(256)
void attn_kernel(const unsigned short* __restrict__ Q,
                 const unsigned short* __restrict__ Kt,
                 const unsigned short* __restrict__ Vt,
                 const int* __restrict__ mask,
                 unsigned short* __restrict__ outp) {
  __shared__ __attribute__((aligned(16))) short Ks[2][64*64];   // [k][d] swizzled
  __shared__ __attribute__((aligned(16))) short Vs[2][64*64];   // [d][k] swizzled
  __shared__ __attribute__((aligned(8)))  unsigned char maskb[256];
  __shared__ int tflag[32];

  int bid = blockIdx.x;                              // 512 blocks
  int bid2 = (bid & 7) * 64 + (bid >> 3);            // XCD swizzle (bijective)
  int bh = bid2 >> 4, qt = bid2 & 15;
  int b = bh >> 4, h = bh & 15;
  int t = threadIdx.x, l = t & 63, wid = t >> 6;
  int hh = l >> 5;                                   // half-lane index

  // ---- mask prologue: thread t packs ints [8t, 8t+8) into byte t ----
  {
    const i32x4* mp = (const i32x4*)(mask + b * S_) + t * 2;
    i32x4 m0 = mp[0], m1 = mp[1];
    unsigned by = (unsigned)(m0[0]!=0) | ((unsigned)(m0[1]!=0)<<1) | ((unsigned)(m0[2]!=0)<<2) | ((unsigned)(m0[3]!=0)<<3)
                | ((unsigned)(m1[0]!=0)<<4) | ((unsigned)(m1[1]!=0)<<5) | ((unsigned)(m1[2]!=0)<<6) | ((unsigned)(m1[3]!=0)<<7);
    maskb[t] = (unsigned char)by;
  }
  __syncthreads();
  if (t < 32) {
    unsigned long long v = ((const unsigned long long*)maskb)[t];
    tflag[t] = (v == 0xFFFFFFFFFFFFFFFFull) ? 1 : 0;
  }

  // ---- Q fragments (B-operand): q-col = l&31, d = 16c + 8hh + j ----
  int q0 = qt*128 + wid*32;
  const unsigned short* qp = Q + ((size_t)bh * S_ + q0 + (l & 31)) * 64 + hh * 8;
  short8_t qf[4];
#pragma unroll
  for (int c = 0; c < 4; ++c) qf[c] = *(const short8_t*)(qp + c*16);

  // ---- staging: wave w covers rows [w*16, w*16+16), 2 glds each for K and V --
  int r_off = wid*16 + (l >> 3);
  int slot_src = (l & 7) ^ (l >> 3);
  const unsigned short* ksrc = Kt + ((size_t)bh * S_ + r_off) * 64 + slot_src * 8;
  const unsigned short* vsrc = Vt + ((size_t)bh * 64 + r_off) * S_ + slot_src * 8;
  int lds_off = wid*2048;

  const float SC = 0.18033688011112042f;             // (1/8) * log2(e)
  float m_run = 0.f, msc = 0.f, l_run = 0.f;
  f32x16 oc0 = {}, oc1 = {};

  // prologue: stage tile 0 into buffer 0
#pragma unroll
  for (int i = 0; i < 2; ++i) {
    glds16(ksrc + (size_t)(i*8) * 64, (char*)Ks[0] + lds_off + i*1024);
    glds16(vsrc + (size_t)(i*8) * S_, (char*)Vs[0] + lds_off + i*1024);
  }

  for (int ti = 0; ti < 32; ++ti) {
    int kt0 = ti << 6;
    int buf = ti & 1;
    __syncthreads();                                 // drains vmcnt -> buf ready
    if (ti < 31) {                                   // prefetch next tile
      int nb = buf ^ 1;
      int nk = kt0 + 64;
#pragma unroll
      for (int i = 0; i < 2; ++i) {
        glds16(ksrc + (size_t)(nk + i*8) * 64, (char*)Ks[nb] + lds_off + i*1024);
        glds16(vsrc + (size_t)(i*8) * S_ + nk, (char*)Vs[nb] + lds_off + i*1024);
      }
    }
    const char* Kb = (const char*)Ks[buf];
    const char* Vb = (const char*)Vs[buf];

    // ---- QK^T (swapped): lane holds q=l&31, 32 k-scores in-register ----
    f32x16 st0 = {}, st1 = {};
#pragma unroll
    for (int c = 0; c < 4; ++c) {
      int row0 = (l & 31);
      int slot = (c*2 + hh) ^ (l & 7);
      short8_t kf0 = *(const short8_t*)(Kb + row0*128 + slot*16);
      short8_t kf1 = *(const short8_t*)(Kb + (row0+32)*128 + slot*16);
      st0 = __builtin_amdgcn_mfma_f32_32x32x16_bf16(kf0, qf[c], st0, 0, 0, 0);
      st1 = __builtin_amdgcn_mfma_f32_32x32x16_bf16(kf1, qf[c], st1, 0, 0, 0);
    }

    // ---- speculative exps off the old running max (defer-max) ----
    float p0[16], p1[16];
#pragma unroll
    for (int r = 0; r < 16; ++r) {
      p0[r] = __builtin_amdgcn_exp2f(fmaf(st0[r], SC, -msc));
      p1[r] = __builtin_amdgcn_exp2f(fmaf(st1[r], SC, -msc));
    }
    // parallel: tile max for the rare-rescale check
    float mx = fmaxf(max16f(st0), max16f(st1));
    mx = fmaxf(mx, __shfl_xor(mx, 32));
    if (__any(mx > m_run + 48.f)) {                  // rare fix-up (never for this data)
      float nm = fmaxf(m_run, mx);
      float fac = __builtin_amdgcn_exp2f((m_run - nm) * SC);
#pragma unroll
      for (int r = 0; r < 16; ++r) { p0[r] *= fac; p1[r] *= fac; }
#pragma unroll
      for (int r = 0; r < 16; ++r) { oc0[r] *= fac; oc1[r] *= fac; }
      l_run *= fac;
      m_run = nm; msc = nm * SC;
    }
    if (!tflag[kt0 >> 6]) {                          // rare: zero masked p
#pragma unroll
      for (int r = 0; r < 16; ++r) {
        int kl = kt0 + (r & 3) + 8*(r >> 2) + 4*hh;
        if (!((maskb[kl >> 3] >> (kl & 7)) & 1)) p0[r] = 0.f;
        kl += 32;
        if (!((maskb[kl >> 3] >> (kl & 7)) & 1)) p1[r] = 0.f;
      }
    }
    l_run += sum16f(p0) + sum16f(p1);

    // ---- repack P -> bf16 B-operand fragments via cvt_pk + permlane32_swap ----
    short8_t pa[4];
    {
      unsigned a0 = pkbf(p0[0],  p0[1]),  b0 = pkbf(p0[4],  p0[5]);
      unsigned a1 = pkbf(p0[2],  p0[3]),  b1 = pkbf(p0[6],  p0[7]);
      plswap(a0, b0); plswap(a1, b1);
      i32x4 w0 = {(int)a0, (int)a1, (int)b0, (int)b1};
      pa[0] = __builtin_bit_cast(short8_t, w0);
      unsigned a2 = pkbf(p0[8],  p0[9]),  b2 = pkbf(p0[12], p0[13]);
      unsigned a3 = pkbf(p0[10], p0[11]), b3 = pkbf(p0[14], p0[15]);
      plswap(a2, b2); plswap(a3, b3);
      i32x4 w1 = {(int)a2, (int)a3, (int)b2, (int)b3};
      pa[1] = __builtin_bit_cast(short8_t, w1);
      unsigned a4 = pkbf(p1[0],  p1[1]),  b4 = pkbf(p1[4],  p1[5]);
      unsigned a5 = pkbf(p1[2],  p1[3]),  b5 = pkbf(p1[6],  p1[7]);
      plswap(a4, b4); plswap(a5, b5);
      i32x4 w2 = {(int)a4, (int)a5, (int)b4, (int)b5};
      pa[2] = __builtin_bit_cast(short8_t, w2);
      unsigned a6 = pkbf(p1[8],  p1[9]),  b6 = pkbf(p1[12], p1[13]);
      unsigned a7 = pkbf(p1[10], p1[11]), b7 = pkbf(p1[14], p1[15]);
      plswap(a6, b6); plswap(a7, b7);
      i32x4 w3 = {(int)a6, (int)a7, (int)b6, (int)b7};
      pa[3] = __builtin_bit_cast(short8_t, w3);
    }

    // ---- PV (swapped): O^T += V^T . P^T ----
#pragma unroll
    for (int kc = 0; kc < 4; ++kc) {
      int row0 = (l & 31);
      int slot = (kc*2 + hh) ^ (l & 7);
      short8_t vf0 = *(const short8_t*)(Vb + row0*128 + slot*16);
      short8_t vf1 = *(const short8_t*)(Vb + (row0+32)*128 + slot*16);
      oc0 = __builtin_amdgcn_mfma_f32_32x32x16_bf16(vf0, pa[kc], oc0, 0, 0, 0);
      oc1 = __builtin_amdgcn_mfma_f32_32x32x16_bf16(vf1, pa[kc], oc1, 0, 0, 0);
    }
  }

  // ---- epilogue: normalize, pack, store ----
  float ltot = l_run + __shfl_xor(l_run, 32);
  float inv = 1.f / ltot;
#pragma unroll
  for (int r = 0; r < 16; ++r) { oc0[r] *= inv; oc1[r] *= inv; }

  unsigned short* obase = outp + ((size_t)b * S_ + q0 + (l & 31)) * C_ + h*64 + hh*8;
#pragma unroll
  for (int dt = 0; dt < 2; ++dt) {
    const f32x16& oc = dt ? oc1 : oc0;
    unsigned a0 = pkbf(oc[0],  oc[1]),  b0 = pkbf(oc[4],  oc[5]);
    unsigned a1 = pkbf(oc[2],  oc[3]),  b1 = pkbf(oc[6],  oc[7]);
    plswap(a0, b0); plswap(a1, b1);
    i32x4 w0 = {(int)a0, (int)a1, (int)b0, (int)b1};
    *(i32x4*)(obase + dt*32) = w0;
    unsigned a2 = pkbf(oc[8],  oc[9]),  b2 = pkbf(oc[12], oc[13]);
    unsigned a3 = pkbf(oc[10], oc[11]), b3 = pkbf(oc[14], oc[15]);
    plswap(a2, b2); plswap(a3, b3);
    i32x4 w1 = {(int)a2, (int)a3, (int)b2, (int)b3};
    *(i32x4*)(obase + dt*32 + 16) = w1;
  }
}

// ---------------- launcher ----------------
extern "C" void kernel_launch(void* const* d_in, const int* in_sizes, int n_in,
                              void* d_out, int out_size, void* d_ws, size_t ws_size,
                              hipStream_t stream) {
  const float* hs = (const float*)d_in[0];
  const int*   msk = (const int*)d_in[1];
  const float* gw = (const float*)d_in[2];
  const float* gb = (const float*)d_in[3];
  const float* Wq = (const float*)d_in[4];
  const float* bq = (const float*)d_in[5];
  const float* Wk = (const float*)d_in[6];
  const float* bk = (const float*)d_in[7];
  const float* Wv = (const float*)d_in[8];
  const float* bv = (const float*)d_in[9];
  const float* Wo = (const float*)d_in[10];
  const float* bo = (const float*)d_in[11];

  char* ws = (char*)d_ws;
  float*  stats = (float*)(ws);
  float2* part  = (float2*)(ws + 256);
  unsigned short* wq_b = (unsigned short*)(ws + 8192);
  unsigned short* wk_b = wq_b + 1048576;
  unsigned short* wv_b = wk_b + 1048576;
  unsigned short* wo_b = wv_b + 1048576;
  unsigned short* x_b  = wo_b + 1048576;     // (B,S,C) bf16
  unsigned short* q_b  = x_b  + 4194304;     // (B,H,S,D)
  unsigned short* k_b  = q_b  + 4194304;     // (B,H,S,D)
  unsigned short* vt_b = k_b  + 4194304;     // (B,H,D,S)
  unsigned short* ao_b = vt_b + 4194304;     // (B,S,C)

  cvt_w4<<<4096, 256, 0, stream>>>(Wq, Wk, Wv, Wo, wq_b);

  stats1<<<512, 256, 0, stream>>>(hs, part);
  stats2<<<2, 256, 0, stream>>>(part, stats);
  normt<<<1024, 256, 0, stream>>>(hs, gw, gb, stats, x_b);

  gemm_nt<0><<<512, 256, 0, stream>>>(x_b, wq_b, bq, nullptr, q_b, 8);
  gemm_nt<0><<<512, 256, 0, stream>>>(x_b, wk_b, bk, nullptr, k_b, 8);
  gemm_nt<1><<<512, 256, 0, stream>>>(wv_b, x_b, bv, nullptr, vt_b, 32);

  attn_kernel<<<512, 256, 0, stream>>>(q_b, k_b, vt_b, msk, ao_b);

  gemm_nt<2><<<512, 256, 0, stream>>>(wo_b, ao_b, bo, hs, d_out, 32);
}

// Round 4
// 134.127 us; speedup vs baseline: 1.4632x; 1.0904x over previous
//
#include <hip/hip_runtime.h>
#include <hip/hip_bf16.h>

#define B_ 2
#define C_ 1024
#define S_ 2048
#define H_ 16
#define KDIM 1024

typedef __attribute__((ext_vector_type(8))) short short8_t;
typedef __attribute__((ext_vector_type(4))) float f32x4;
typedef __attribute__((ext_vector_type(16))) float f32x16;
typedef __attribute__((ext_vector_type(4))) int i32x4;

__device__ __forceinline__ void glds16(const void* g, void* l) {
  __builtin_amdgcn_global_load_lds((const __attribute__((address_space(1))) void*)g,
                                   (__attribute__((address_space(3))) void*)l, 16, 0, 0);
}

__device__ __forceinline__ unsigned short f2bf(float f) {
  __hip_bfloat16 h = __float2bfloat16(f);
  return __builtin_bit_cast(unsigned short, h);
}

__device__ __forceinline__ unsigned pkbf(float lo, float hi) {
  unsigned r;
  asm("v_cvt_pk_bf16_f32 %0, %1, %2" : "=v"(r) : "v"(lo), "v"(hi));
  return r;
}

__device__ __forceinline__ void plswap(unsigned &a, unsigned &b) {
  asm("v_permlane32_swap_b32 %0, %1" : "+v"(a), "+v"(b));
}

__device__ __forceinline__ float max16v(const f32x16& v) {
  float a = fmaxf(fmaxf(v[0], v[1]),  fmaxf(v[2], v[3]));
  float b = fmaxf(fmaxf(v[4], v[5]),  fmaxf(v[6], v[7]));
  float c = fmaxf(fmaxf(v[8], v[9]),  fmaxf(v[10], v[11]));
  float d = fmaxf(fmaxf(v[12], v[13]), fmaxf(v[14], v[15]));
  return fmaxf(fmaxf(a, b), fmaxf(c, d));
}

__device__ __forceinline__ float sum16v(const f32x16& p) {
  float a = (p[0] + p[1]) + (p[2] + p[3]);
  float b = (p[4] + p[5]) + (p[6] + p[7]);
  float c = (p[8] + p[9]) + (p[10] + p[11]);
  float d = (p[12] + p[13]) + (p[14] + p[15]);
  return (a + b) + (c + d);
}

// ---------------- weight fp32 -> bf16 (all 4 in one launch) ----------------
__global__ __launch_bounds__(256) void cvt_w4(const float* __restrict__ a,
                                              const float* __restrict__ b,
                                              const float* __restrict__ c,
                                              const float* __restrict__ d,
                                              unsigned short* __restrict__ o) {
  int g = blockIdx.x >> 10;
  const float* src = (g == 0) ? a : (g == 1) ? b : (g == 2) ? c : d;
  int i = (blockIdx.x & 1023) * 256 + threadIdx.x;
  float4 v = ((const float4*)src)[i];
  short4 r;
  r.x = (short)f2bf(v.x); r.y = (short)f2bf(v.y);
  r.z = (short)f2bf(v.z); r.w = (short)f2bf(v.w);
  ((short4*)(o))[(size_t)g * 262144 + i] = r;
}

// ---------------- per-batch stats (two-stage, deterministic) ----------------
__global__ __launch_bounds__(256) void stats1(const float* __restrict__ x,
                                              float2* __restrict__ part) {
  int bid = blockIdx.x;                             // 512 blocks
  int b = bid >> 8, chunk = bid & 255;
  const float4* p = (const float4*)(x + (size_t)b*(C_*S_) + (size_t)chunk*8192);
  int t = threadIdx.x;
  float s = 0.f, q = 0.f;
#pragma unroll
  for (int i = 0; i < 8; ++i) {
    float4 v = p[t + i*256];
    s += v.x + v.y + v.z + v.w;
    q += v.x*v.x + v.y*v.y + v.z*v.z + v.w*v.w;
  }
#pragma unroll
  for (int d = 1; d < 64; d <<= 1) { s += __shfl_xor(s, d); q += __shfl_xor(q, d); }
  __shared__ float2 wsum[4];
  if ((t & 63) == 0) wsum[t >> 6] = make_float2(s, q);
  __syncthreads();
  if (t == 0) {
    float S = 0.f, Q = 0.f;
    for (int i = 0; i < 4; ++i) { S += wsum[i].x; Q += wsum[i].y; }
    part[bid] = make_float2(S, Q);
  }
}

__global__ __launch_bounds__(256) void stats2(const float2* __restrict__ part,
                                              float* __restrict__ stats) {
  int b = blockIdx.x;
  int t = threadIdx.x;
  float2 v = part[b*256 + t];
  float s = v.x, q = v.y;
#pragma unroll
  for (int d = 1; d < 64; d <<= 1) { s += __shfl_xor(s, d); q += __shfl_xor(q, d); }
  __shared__ float2 wsum[4];
  if ((t & 63) == 0) wsum[t >> 6] = make_float2(s, q);
  __syncthreads();
  if (t == 0) {
    float S = 0.f, Q = 0.f;
    for (int i = 0; i < 4; ++i) { S += wsum[i].x; Q += wsum[i].y; }
    const float invN = 1.0f / (float)(C_*S_);
    float mean = S * invN;
    float var = Q * invN - mean*mean;
    stats[b*2]   = mean;
    stats[b*2+1] = rsqrtf(var + 1e-5f);
  }
}

// ---------------- normalize + transpose (B,C,S)f32 -> (B,S,C)bf16 ----------------
__global__ __launch_bounds__(256) void normt(const float* __restrict__ x,
                                             const float* __restrict__ gw,
                                             const float* __restrict__ gb,
                                             const float* __restrict__ stats,
                                             unsigned short* __restrict__ xt) {
  __shared__ short lds[64*72];
  int bid = blockIdx.x;                              // 1024 blocks
  int b = bid >> 9, rem = bid & 511;
  int ct = rem >> 5, st = rem & 31;
  float mean = stats[b*2], rstd = stats[b*2+1];
  int t = threadIdx.x;
  int r = t >> 2, seg = t & 3;
  int c = ct*64 + r;
  float wsc = gw[c] * rstd;
  float bof = gb[c] - mean * wsc;
  const float4* src = (const float4*)(x + (size_t)b*(C_*S_) + (size_t)c*S_ + st*64 + seg*16);
#pragma unroll
  for (int j = 0; j < 4; ++j) {
    float4 v = src[j];
    int sl = seg*16 + j*4;
    lds[(sl+0)*72 + r] = (short)f2bf(v.x*wsc + bof);
    lds[(sl+1)*72 + r] = (short)f2bf(v.y*wsc + bof);
    lds[(sl+2)*72 + r] = (short)f2bf(v.z*wsc + bof);
    lds[(sl+3)*72 + r] = (short)f2bf(v.w*wsc + bof);
  }
  __syncthreads();
  int sl = t >> 2;
  __attribute__((aligned(16))) unsigned short tmp[16];
#pragma unroll
  for (int j = 0; j < 16; ++j) tmp[j] = (unsigned short)lds[sl*72 + seg*16 + j];
  unsigned short* dst = xt + ((size_t)b*S_ + st*64 + sl) * C_ + ct*64 + seg*16;
  *(short8_t*)dst       = *(const short8_t*)tmp;
  *(short8_t*)(dst + 8) = *(const short8_t*)(tmp + 8);
}

// ---------------- NT GEMM: C[m,n] = sum_k A[m,k]*B[n,k] (K=1024) ----------------
template<int EPI>
__global__ __launch_bounds__(256)
void gemm_nt(const unsigned short* __restrict__ A,
             const unsigned short* __restrict__ Bm,
             const float* __restrict__ bias,
             const float* __restrict__ resid,
             void* __restrict__ outp,
             int nbn) {
  __shared__ __attribute__((aligned(16))) short As[64*64];
  __shared__ __attribute__((aligned(16))) short Bs[128*64];
  int nwg = gridDim.x;
  int bid = blockIdx.x;
  int cpx = nwg >> 3;                                // grid % 8 == 0
  int sbid = (bid & 7) * cpx + (bid >> 3);
  int bm = sbid / nbn, bn = sbid % nbn;
  int m0 = bm << 6, n0 = bn << 7;
  int t = threadIdx.x;
  int l = t & 63, wid = t >> 6;

  int r_st = t >> 3;                                 // 0..31
  int slot_src = (t & 7) ^ (r_st & 7);               // pre-swizzled source slot
  const unsigned short* a_src = A + (size_t)(m0 + r_st) * KDIM + slot_src * 8;
  const unsigned short* b_src = Bm + (size_t)(n0 + r_st) * KDIM + slot_src * 8;
  char* As_base = (char*)As + wid*1024;
  char* Bs_base = (char*)Bs + wid*1024;

  f32x4 acc[4][2] = {};

  for (int kt = 0; kt < KDIM; kt += 64) {
    __syncthreads();
    glds16(a_src + kt, As_base);
    glds16(a_src + (size_t)32*KDIM + kt, As_base + 4096);
#pragma unroll
    for (int i = 0; i < 4; ++i)
      glds16(b_src + (size_t)(i*32)*KDIM + kt, Bs_base + i*4096);
    __syncthreads();
#pragma unroll
    for (int kk = 0; kk < 2; ++kk) {
      short8_t af[4], bfr[2];
#pragma unroll
      for (int mi = 0; mi < 4; ++mi) {
        int row = mi*16 + (l & 15);
        int slot = (kk*4 + (l >> 4)) ^ (row & 7);
        af[mi] = *(const short8_t*)((const char*)As + row*128 + slot*16);
      }
#pragma unroll
      for (int ni = 0; ni < 2; ++ni) {
        int row = wid*32 + ni*16 + (l & 15);
        int slot = (kk*4 + (l >> 4)) ^ (row & 7);
        bfr[ni] = *(const short8_t*)((const char*)Bs + row*128 + slot*16);
      }
#pragma unroll
      for (int mi = 0; mi < 4; ++mi)
#pragma unroll
        for (int ni = 0; ni < 2; ++ni)
          acc[mi][ni] = __builtin_amdgcn_mfma_f32_16x16x32_bf16(af[mi], bfr[ni], acc[mi][ni], 0, 0, 0);
    }
  }

#pragma unroll
  for (int mi = 0; mi < 4; ++mi) {
#pragma unroll
    for (int ni = 0; ni < 2; ++ni) {
#pragma unroll
      for (int r = 0; r < 4; ++r) {
        int gm = m0 + mi*16 + ((l >> 4) << 2) + r;
        int gn = n0 + wid*32 + ni*16 + (l & 15);
        float v = acc[mi][ni][r];
        if (EPI == 0) {
          v += bias[gn];
          size_t off = ((size_t)((gm >> 11)*H_ + (gn >> 6)) * S_ + (gm & 2047)) * 64 + (gn & 63);
          ((unsigned short*)outp)[off] = f2bf(v);
        } else {
          v += bias[gm];
          size_t off = (size_t)(gn >> 11) * ((size_t)C_*S_) + (size_t)gm * S_ + (gn & 2047);
          if (EPI == 1) {
            ((unsigned short*)outp)[off] = f2bf(v);
          } else {
            ((float*)outp)[off] = v + resid[off];
          }
        }
      }
    }
  }
}

// ---------------- flash attention, swapped 32x32, split-KV 8-wave -------------
// Q,K: (B,H,S,D) bf16; Vt: (B,H,D,S) bf16; out ao: (B,S,C) bf16
// 512 blocks x 512 thr. Waves 0-3: q-subtiles over KV[0:1024); waves 4-7: same
// q over KV[1024:2048). LDS-merge epilogue. 4 waves/SIMD occupancy.
__global__ __launch_bounds__(512, 4)
void attn_kernel(const unsigned short* __restrict__ Q,
                 const unsigned short* __restrict__ Kt,
                 const unsigned short* __restrict__ Vt,
                 const int* __restrict__ mask,
                 unsigned short* __restrict__ outp) {
  // layout: K: quad*16384 + buf*8192 + row*128 + slot*16 ; V: +32768 same
  __shared__ __attribute__((aligned(16))) char lds[65536];
  __shared__ __attribute__((aligned(8)))  unsigned char maskb[256];
  __shared__ int tflag[32];

  int bid = blockIdx.x;                              // 512 blocks
  int bid2 = (bid & 7) * 64 + (bid >> 3);            // XCD swizzle (bijective)
  int bh = bid2 >> 4, qt = bid2 & 15;
  int b = bh >> 4, h = bh & 15;
  int t = threadIdx.x, l = t & 63, wid = t >> 6;
  int quad = wid >> 2, qw = wid & 3;
  int hh = l >> 5;                                   // half-lane index

  // ---- mask prologue: thread t<256 packs ints [8t, 8t+8) into byte t ----
  if (t < 256) {
    const i32x4* mp = (const i32x4*)(mask + b * S_) + t * 2;
    i32x4 m0 = mp[0], m1 = mp[1];
    unsigned by = (unsigned)(m0[0]!=0) | ((unsigned)(m0[1]!=0)<<1) | ((unsigned)(m0[2]!=0)<<2) | ((unsigned)(m0[3]!=0)<<3)
                | ((unsigned)(m1[0]!=0)<<4) | ((unsigned)(m1[1]!=0)<<5) | ((unsigned)(m1[2]!=0)<<6) | ((unsigned)(m1[3]!=0)<<7);
    maskb[t] = (unsigned char)by;
  }
  __syncthreads();
  if (t < 32) {
    unsigned long long v = ((const unsigned long long*)maskb)[t];
    tflag[t] = (v == 0xFFFFFFFFFFFFFFFFull) ? 1 : 0;
  }
  // visible after the first tile barrier

  // ---- Q fragments (B-operand): q-col = l&31, d = 16c + 8hh + j ----
  int q0 = qt*128 + qw*32;
  const unsigned short* qp = Q + ((size_t)bh * S_ + q0 + (l & 31)) * 64 + hh * 8;
  short8_t qf[4];
#pragma unroll
  for (int c = 0; c < 4; ++c) qf[c] = *(const short8_t*)(qp + c*16);

  // ---- staging: wave stages 16 K-rows + 16 V-rows of its quad's tile ----
  int kbase = quad << 10;
  int row_st = qw*16 + (l >> 3);
  int slot_st = (l & 7) ^ (l >> 3);
  const unsigned short* kp = Kt + ((size_t)bh * S_ + kbase + row_st) * 64 + slot_st * 8;
  const unsigned short* vp = Vt + ((size_t)bh * 64 + row_st) * S_ + kbase + slot_st * 8;
  char* kdst = lds + quad*16384 + qw*2048;
  char* vdst = kdst + 32768;

  // ---- ds-read byte offsets (tile-invariant; buf parity folds to imm) ----
  unsigned ko[8];
#pragma unroll
  for (int c = 0; c < 4; ++c) {
    unsigned slot = (unsigned)((c*2 + hh) ^ (l & 7)) * 16u;
    ko[c]   = (unsigned)(quad*16384) + (unsigned)(l & 31)*128u + slot;
    ko[c+4] = ko[c] + 4096u;
  }

  const float SC = 0.18033688011112042f;             // (1/8) * log2(e)
  float m_run = 0.f, msc = 0.f, l_run = 0.f;
  f32x16 oc0 = {}, oc1 = {};

  // prologue: stage tile 0 into buffer 0
  glds16(kp,                kdst);
  glds16(kp + 8*64,         kdst + 1024);
  glds16(vp,                vdst);
  glds16(vp + (size_t)8*S_, vdst + 1024);
  const unsigned short* kn = kp + 64*64;
  const unsigned short* vn = vp + 64;
  int lt = 0;

#define ATILE(BUF)                                                              \
  do {                                                                          \
    __syncthreads();                                                            \
    glds16(kn,                kdst + ((BUF)^1)*8192);                           \
    glds16(kn + 8*64,         kdst + ((BUF)^1)*8192 + 1024);                    \
    glds16(vn,                vdst + ((BUF)^1)*8192);                           \
    glds16(vn + (size_t)8*S_, vdst + ((BUF)^1)*8192 + 1024);                    \
    kn += 4096; vn += 64;                                                       \
    f32x16 st0 = {}, st1 = {};                                                  \
    __builtin_amdgcn_s_setprio(1);                                              \
    _Pragma("unroll")                                                           \
    for (int c = 0; c < 4; ++c) {                                               \
      short8_t kf0 = *(const short8_t*)(lds + ko[c]   + (BUF)*8192);            \
      short8_t kf1 = *(const short8_t*)(lds + ko[c+4] + (BUF)*8192);            \
      st0 = __builtin_amdgcn_mfma_f32_32x32x16_bf16(kf0, qf[c], st0, 0, 0, 0);  \
      st1 = __builtin_amdgcn_mfma_f32_32x32x16_bf16(kf1, qf[c], st1, 0, 0, 0);  \
    }                                                                           \
    __builtin_amdgcn_s_setprio(0);                                              \
    _Pragma("unroll")                                                           \
    for (int r = 0; r < 16; ++r) {                                              \
      st0[r] = __builtin_amdgcn_exp2f(fmaf(st0[r], SC, -msc));                  \
      st1[r] = __builtin_amdgcn_exp2f(fmaf(st1[r], SC, -msc));                  \
    }                                                                           \
    if (!tflag[(kbase >> 6) + lt]) {                                            \
      _Pragma("unroll")                                                         \
      for (int r = 0; r < 16; ++r) {                                            \
        int kl = kbase + lt*64 + (r & 3) + 8*(r >> 2) + 4*hh;                   \
        if (!((maskb[kl >> 3] >> (kl & 7)) & 1)) st0[r] = 0.f;                  \
        kl += 32;                                                               \
        if (!((maskb[kl >> 3] >> (kl & 7)) & 1)) st1[r] = 0.f;                  \
      }                                                                         \
    }                                                                           \
    float pmax = fmaxf(max16v(st0), max16v(st1));                               \
    l_run += sum16v(st0) + sum16v(st1);                                         \
    short8_t pa[4];                                                             \
    {                                                                           \
      unsigned a0 = pkbf(st0[0],  st0[1]),  b0 = pkbf(st0[4],  st0[5]);         \
      unsigned a1 = pkbf(st0[2],  st0[3]),  b1 = pkbf(st0[6],  st0[7]);         \
      plswap(a0, b0); plswap(a1, b1);                                           \
      i32x4 w0 = {(int)a0, (int)a1, (int)b0, (int)b1};                          \
      pa[0] = __builtin_bit_cast(short8_t, w0);                                 \
      unsigned a2 = pkbf(st0[8],  st0[9]),  b2 = pkbf(st0[12], st0[13]);        \
      unsigned a3 = pkbf(st0[10], st0[11]), b3 = pkbf(st0[14], st0[15]);        \
      plswap(a2, b2); plswap(a3, b3);                                           \
      i32x4 w1 = {(int)a2, (int)a3, (int)b2, (int)b3};                          \
      pa[1] = __builtin_bit_cast(short8_t, w1);                                 \
      unsigned a4 = pkbf(st1[0],  st1[1]),  b4 = pkbf(st1[4],  st1[5]);         \
      unsigned a5 = pkbf(st1[2],  st1[3]),  b5 = pkbf(st1[6],  st1[7]);         \
      plswap(a4, b4); plswap(a5, b5);                                           \
      i32x4 w2 = {(int)a4, (int)a5, (int)b4, (int)b5};                          \
      pa[2] = __builtin_bit_cast(short8_t, w2);                                 \
      unsigned a6 = pkbf(st1[8],  st1[9]),  b6 = pkbf(st1[12], st1[13]);        \
      unsigned a7 = pkbf(st1[10], st1[11]), b7 = pkbf(st1[14], st1[15]);        \
      plswap(a6, b6); plswap(a7, b7);                                           \
      i32x4 w3 = {(int)a6, (int)a7, (int)b6, (int)b7};                          \
      pa[3] = __builtin_bit_cast(short8_t, w3);                                 \
    }                                                                           \
    __builtin_amdgcn_s_setprio(1);                                              \
    _Pragma("unroll")                                                           \
    for (int kc = 0; kc < 4; ++kc) {                                            \
      short8_t vf0 = *(const short8_t*)(lds + ko[kc]   + 32768 + (BUF)*8192);   \
      short8_t vf1 = *(const short8_t*)(lds + ko[kc+4] + 32768 + (BUF)*8192);   \
      oc0 = __builtin_amdgcn_mfma_f32_32x32x16_bf16(vf0, pa[kc], oc0, 0, 0, 0); \
      oc1 = __builtin_amdgcn_mfma_f32_32x32x16_bf16(vf1, pa[kc], oc1, 0, 0, 0); \
    }                                                                           \
    __builtin_amdgcn_s_setprio(0);                                              \
    if (__any(pmax > 148.0f)) {                                                 \
      float pm = fmaxf(pmax, __shfl_xor(pmax, 32));                             \
      float smax = (__log2f(pm) + msc) / SC;                                    \
      float nm = fmaxf(m_run, smax);                                            \
      float fac = __builtin_amdgcn_exp2f((m_run - nm) * SC);                    \
      _Pragma("unroll")                                                         \
      for (int r = 0; r < 16; ++r) { oc0[r] *= fac; oc1[r] *= fac; }            \
      l_run *= fac; m_run = nm; msc = nm * SC;                                  \
    }                                                                           \
    ++lt;                                                                       \
  } while (0)

  for (int tp = 0; tp < 8; ++tp) {
    ATILE(0);
    ATILE(1);
  }
#undef ATILE

  // ---- merge epilogue: quad1 -> LDS, quad0 combines + stores ----
  __syncthreads();                                   // also drains garbage glds
  if (quad == 1) {
    char* obuf = lds + qw*8192 + l*128;
#pragma unroll
    for (int j = 0; j < 4; ++j) {
      f32x4 u0 = { oc0[4*j], oc0[4*j+1], oc0[4*j+2], oc0[4*j+3] };
      *(f32x4*)(obuf + ((j ^ (l & 7)) * 16)) = u0;
      f32x4 u1 = { oc1[4*j], oc1[4*j+1], oc1[4*j+2], oc1[4*j+3] };
      *(f32x4*)(obuf + (((j+4) ^ (l & 7)) * 16)) = u1;
    }
    *(float2*)(lds + 32768 + (qw*64 + l)*8) = make_float2(l_run, m_run);
  }
  __syncthreads();
  if (quad == 0) {
    float2 lm1 = *(const float2*)(lds + 32768 + (qw*64 + l)*8);
    float M  = fmaxf(m_run, lm1.y);
    float a0 = __builtin_amdgcn_exp2f((m_run - M) * SC);
    float a1 = __builtin_amdgcn_exp2f((lm1.y - M) * SC);
    float lc = l_run * a0 + lm1.x * a1;
    float ltot = lc + __shfl_xor(lc, 32);
    float inv = 1.f / ltot;
    float s0 = a0 * inv, s1 = a1 * inv;
    const char* obuf = lds + qw*8192 + l*128;
#pragma unroll
    for (int j = 0; j < 4; ++j) {
      f32x4 u0 = *(const f32x4*)(obuf + ((j ^ (l & 7)) * 16));
      oc0[4*j]   = oc0[4*j]  *s0 + u0[0]*s1;
      oc0[4*j+1] = oc0[4*j+1]*s0 + u0[1]*s1;
      oc0[4*j+2] = oc0[4*j+2]*s0 + u0[2]*s1;
      oc0[4*j+3] = oc0[4*j+3]*s0 + u0[3]*s1;
      f32x4 u1 = *(const f32x4*)(obuf + (((j+4) ^ (l & 7)) * 16));
      oc1[4*j]   = oc1[4*j]  *s0 + u1[0]*s1;
      oc1[4*j+1] = oc1[4*j+1]*s0 + u1[1]*s1;
      oc1[4*j+2] = oc1[4*j+2]*s0 + u1[2]*s1;
      oc1[4*j+3] = oc1[4*j+3]*s0 + u1[3]*s1;
    }

    unsigned short* obase = outp + ((size_t)b * S_ + q0 + (l & 31)) * C_ + h*64 + hh*8;
#pragma unroll
    for (int dt = 0; dt < 2; ++dt) {
      const f32x16& oc = dt ? oc1 : oc0;
      unsigned a0w = pkbf(oc[0],  oc[1]),  b0w = pkbf(oc[4],  oc[5]);
      unsigned a1w = pkbf(oc[2],  oc[3]),  b1w = pkbf(oc[6],  oc[7]);
      plswap(a0w, b0w); plswap(a1w, b1w);
      i32x4 w0 = {(int)a0w, (int)a1w, (int)b0w, (int)b1w};
      *(i32x4*)(obase + dt*32) = w0;
      unsigned a2w = pkbf(oc[8],  oc[9]),  b2w = pkbf(oc[12], oc[13]);
      unsigned a3w = pkbf(oc[10], oc[11]), b3w = pkbf(oc[14], oc[15]);
      plswap(a2w, b2w); plswap(a3w, b3w);
      i32x4 w1 = {(int)a2w, (int)a3w, (int)b2w, (int)b3w};
      *(i32x4*)(obase + dt*32 + 16) = w1;
    }
  }
}

// ---------------- launcher ----------------
extern "C" void kernel_launch(void* const* d_in, const int* in_sizes, int n_in,
                              void* d_out, int out_size, void* d_ws, size_t ws_size,
                              hipStream_t stream) {
  const float* hs = (const float*)d_in[0];
  const int*   msk = (const int*)d_in[1];
  const float* gw = (const float*)d_in[2];
  const float* gb = (const float*)d_in[3];
  const float* Wq = (const float*)d_in[4];
  const float* bq = (const float*)d_in[5];
  const float* Wk = (const float*)d_in[6];
  const float* bk = (const float*)d_in[7];
  const float* Wv = (const float*)d_in[8];
  const float* bv = (const float*)d_in[9];
  const float* Wo = (const float*)d_in[10];
  const float* bo = (const float*)d_in[11];

  char* ws = (char*)d_ws;
  float*  stats = (float*)(ws);
  float2* part  = (float2*)(ws + 256);
  unsigned short* wq_b = (unsigned short*)(ws + 8192);
  unsigned short* wk_b = wq_b + 1048576;
  unsigned short* wv_b = wk_b + 1048576;
  unsigned short* wo_b = wv_b + 1048576;
  unsigned short* x_b  = wo_b + 1048576;     // (B,S,C) bf16
  unsigned short* q_b  = x_b  + 4194304;     // (B,H,S,D)
  unsigned short* k_b  = q_b  + 4194304;     // (B,H,S,D)
  unsigned short* vt_b = k_b  + 4194304;     // (B,H,D,S)
  unsigned short* ao_b = vt_b + 4194304;     // (B,S,C)

  cvt_w4<<<4096, 256, 0, stream>>>(Wq, Wk, Wv, Wo, wq_b);

  stats1<<<512, 256, 0, stream>>>(hs, part);
  stats2<<<2, 256, 0, stream>>>(part, stats);
  normt<<<1024, 256, 0, stream>>>(hs, gw, gb, stats, x_b);

  gemm_nt<0><<<512, 256, 0, stream>>>(x_b, wq_b, bq, nullptr, q_b, 8);
  gemm_nt<0><<<512, 256, 0, stream>>>(x_b, wk_b, bk, nullptr, k_b, 8);
  gemm_nt<1><<<512, 256, 0, stream>>>(wv_b, x_b, bv, nullptr, vt_b, 32);

  attn_kernel<<<512, 512, 0, stream>>>(q_b, k_b, vt_b, msk, ao_b);

  gemm_nt<2><<<512, 256, 0, stream>>>(wo_b, ao_b, bo, hs, d_out, 32);
}

// Round 7
// 124.070 us; speedup vs baseline: 1.5818x; 1.0811x over previous
//
#include <hip/hip_runtime.h>
#include <hip/hip_bf16.h>

#define B_ 2
#define C_ 1024
#define S_ 2048
#define H_ 16
#define KDIM 1024

typedef __attribute__((ext_vector_type(8))) short short8_t;
typedef __attribute__((ext_vector_type(4))) float f32x4;
typedef __attribute__((ext_vector_type(16))) float f32x16;
typedef __attribute__((ext_vector_type(4))) int i32x4;

__device__ __forceinline__ void glds16(const void* g, void* l) {
  __builtin_amdgcn_global_load_lds((const __attribute__((address_space(1))) void*)g,
                                   (__attribute__((address_space(3))) void*)l, 16, 0, 0);
}

__device__ __forceinline__ unsigned short f2bf(float f) {
  __hip_bfloat16 h = __float2bfloat16(f);
  return __builtin_bit_cast(unsigned short, h);
}

__device__ __forceinline__ unsigned pkbf(float lo, float hi) {
  unsigned r;
  asm("v_cvt_pk_bf16_f32 %0, %1, %2" : "=v"(r) : "v"(lo), "v"(hi));
  return r;
}

__device__ __forceinline__ void plswap(unsigned &a, unsigned &b) {
  asm("v_permlane32_swap_b32 %0, %1" : "+v"(a), "+v"(b));
}

__device__ __forceinline__ float max3f(float a, float b, float c) {
  float r;
  asm("v_max3_f32 %0, %1, %2, %3" : "=v"(r) : "v"(a), "v"(b), "v"(c));
  return r;
}

// max over 16 values with v_max3 tree (8 ops)
__device__ __forceinline__ float max16v(const f32x16& v) {
  float a = max3f(v[0], v[1], v[2]);
  float b = max3f(v[3], v[4], v[5]);
  float c = max3f(v[6], v[7], v[8]);
  float d = max3f(v[9], v[10], v[11]);
  float e = max3f(v[12], v[13], v[14]);
  float f = max3f(a, b, v[15]);
  float g = max3f(c, d, e);
  return fmaxf(f, g);
}

// ---------------- weight fp32 -> bf16 (all 4 in one launch) ----------------
__global__ __launch_bounds__(256) void cvt_w4(const float* __restrict__ a,
                                              const float* __restrict__ b,
                                              const float* __restrict__ c,
                                              const float* __restrict__ d,
                                              unsigned short* __restrict__ o) {
  int g = blockIdx.x >> 10;
  const float* src = (g == 0) ? a : (g == 1) ? b : (g == 2) ? c : d;
  int i = (blockIdx.x & 1023) * 256 + threadIdx.x;
  float4 v = ((const float4*)src)[i];
  short4 r;
  r.x = (short)f2bf(v.x); r.y = (short)f2bf(v.y);
  r.z = (short)f2bf(v.z); r.w = (short)f2bf(v.w);
  ((short4*)(o))[(size_t)g * 262144 + i] = r;
}

// ---------------- per-batch stats (two-stage, deterministic) ----------------
__global__ __launch_bounds__(256) void stats1(const float* __restrict__ x,
                                              float2* __restrict__ part) {
  int bid = blockIdx.x;                             // 512 blocks
  int b = bid >> 8, chunk = bid & 255;
  const float4* p = (const float4*)(x + (size_t)b*(C_*S_) + (size_t)chunk*8192);
  int t = threadIdx.x;
  float s = 0.f, q = 0.f;
#pragma unroll
  for (int i = 0; i < 8; ++i) {
    float4 v = p[t + i*256];
    s += v.x + v.y + v.z + v.w;
    q += v.x*v.x + v.y*v.y + v.z*v.z + v.w*v.w;
  }
#pragma unroll
  for (int d = 1; d < 64; d <<= 1) { s += __shfl_xor(s, d); q += __shfl_xor(q, d); }
  __shared__ float2 wsum[4];
  if ((t & 63) == 0) wsum[t >> 6] = make_float2(s, q);
  __syncthreads();
  if (t == 0) {
    float S = 0.f, Q = 0.f;
    for (int i = 0; i < 4; ++i) { S += wsum[i].x; Q += wsum[i].y; }
    part[bid] = make_float2(S, Q);
  }
}

__global__ __launch_bounds__(256) void stats2(const float2* __restrict__ part,
                                              float* __restrict__ stats) {
  int b = blockIdx.x;
  int t = threadIdx.x;
  float2 v = part[b*256 + t];
  float s = v.x, q = v.y;
#pragma unroll
  for (int d = 1; d < 64; d <<= 1) { s += __shfl_xor(s, d); q += __shfl_xor(q, d); }
  __shared__ float2 wsum[4];
  if ((t & 63) == 0) wsum[t >> 6] = make_float2(s, q);
  __syncthreads();
  if (t == 0) {
    float S = 0.f, Q = 0.f;
    for (int i = 0; i < 4; ++i) { S += wsum[i].x; Q += wsum[i].y; }
    const float invN = 1.0f / (float)(C_*S_);
    float mean = S * invN;
    float var = Q * invN - mean*mean;
    stats[b*2]   = mean;
    stats[b*2+1] = rsqrtf(var + 1e-5f);
  }
}

// ---------------- normalize + transpose (B,C,S)f32 -> (B,S,C)bf16 ----------------
__global__ __launch_bounds__(256) void normt(const float* __restrict__ x,
                                             const float* __restrict__ gw,
                                             const float* __restrict__ gb,
                                             const float* __restrict__ stats,
                                             unsigned short* __restrict__ xt) {
  __shared__ short lds[64*72];
  int bid = blockIdx.x;                              // 1024 blocks
  int b = bid >> 9, rem = bid & 511;
  int ct = rem >> 5, st = rem & 31;
  float mean = stats[b*2], rstd = stats[b*2+1];
  int t = threadIdx.x;
  int r = t >> 2, seg = t & 3;
  int c = ct*64 + r;
  float wsc = gw[c] * rstd;
  float bof = gb[c] - mean * wsc;
  const float4* src = (const float4*)(x + (size_t)b*(C_*S_) + (size_t)c*S_ + st*64 + seg*16);
#pragma unroll
  for (int j = 0; j < 4; ++j) {
    float4 v = src[j];
    int sl = seg*16 + j*4;
    lds[(sl+0)*72 + r] = (short)f2bf(v.x*wsc + bof);
    lds[(sl+1)*72 + r] = (short)f2bf(v.y*wsc + bof);
    lds[(sl+2)*72 + r] = (short)f2bf(v.z*wsc + bof);
    lds[(sl+3)*72 + r] = (short)f2bf(v.w*wsc + bof);
  }
  __syncthreads();
  int sl = t >> 2;
  __attribute__((aligned(16))) unsigned short tmp[16];
#pragma unroll
  for (int j = 0; j < 16; ++j) tmp[j] = (unsigned short)lds[sl*72 + seg*16 + j];
  unsigned short* dst = xt + ((size_t)b*S_ + st*64 + sl) * C_ + ct*64 + seg*16;
  *(short8_t*)dst       = *(const short8_t*)tmp;
  *(short8_t*)(dst + 8) = *(const short8_t*)(tmp + 8);
}

// ---------------- fused Q+K GEMM, 128x128 tile (m97 structure) ----------------
// A = x_b (4096 x 1024), Bm = [Wq; Wk] bf16 (2048 x 1024)
// out: q_b then k_b contiguous, each (B,H,S,D) bf16
__global__ __launch_bounds__(256)
void gemm_qk(const unsigned short* __restrict__ A,
             const unsigned short* __restrict__ Bm,
             const float* __restrict__ bq,
             const float* __restrict__ bk,
             unsigned short* __restrict__ outp) {
  __shared__ __attribute__((aligned(16))) short As[128*64];
  __shared__ __attribute__((aligned(16))) short Bs[128*64];
  int bid = blockIdx.x;                              // 512 blocks
  int sbid = (bid & 7) * 64 + (bid >> 3);            // XCD swizzle
  int bm = sbid >> 4, bn = sbid & 15;
  int m0 = bm << 7, n0 = bn << 7;
  int t = threadIdx.x, l = t & 63, wid = t >> 6;
  int wr = wid >> 1, wc = wid & 1;

  int rsb = wid*8 + (l >> 3);                        // staging row 0..31
  int slot_src = (l & 7) ^ (l >> 3);
  const unsigned short* a_src = A + (size_t)(m0 + rsb) * KDIM + slot_src * 8;
  const unsigned short* b_src = Bm + (size_t)(n0 + rsb) * KDIM + slot_src * 8;
  char* adst = (char*)As + wid*1024;
  char* bdst = (char*)Bs + wid*1024;

  f32x4 acc[4][4] = {};

  for (int kt = 0; kt < KDIM; kt += 64) {
    __syncthreads();
#pragma unroll
    for (int i = 0; i < 4; ++i) {
      glds16(a_src + (size_t)(i*32)*KDIM + kt, adst + i*4096);
      glds16(b_src + (size_t)(i*32)*KDIM + kt, bdst + i*4096);
    }
    __syncthreads();
#pragma unroll
    for (int kk = 0; kk < 2; ++kk) {
      short8_t af[4], bf[4];
#pragma unroll
      for (int mi = 0; mi < 4; ++mi) {
        int row = wr*64 + mi*16 + (l & 15);
        int slot = (kk*4 + (l >> 4)) ^ (row & 7);
        af[mi] = *(const short8_t*)((const char*)As + row*128 + slot*16);
      }
#pragma unroll
      for (int ni = 0; ni < 4; ++ni) {
        int row = wc*64 + ni*16 + (l & 15);
        int slot = (kk*4 + (l >> 4)) ^ (row & 7);
        bf[ni] = *(const short8_t*)((const char*)Bs + row*128 + slot*16);
      }
#pragma unroll
      for (int mi = 0; mi < 4; ++mi)
#pragma unroll
        for (int ni = 0; ni < 4; ++ni)
          acc[mi][ni] = __builtin_amdgcn_mfma_f32_16x16x32_bf16(af[mi], bf[ni], acc[mi][ni], 0, 0, 0);
    }
  }

  int gcol0 = n0 + wc*64;                            // uniform per wave
  const float* bp = (gcol0 & 1024) ? bk : bq;
  unsigned short* ob = outp + ((gcol0 & 1024) ? 4194304u : 0u);
  int hd0 = gcol0 & 1023;
#pragma unroll
  for (int mi = 0; mi < 4; ++mi)
#pragma unroll
    for (int ni = 0; ni < 4; ++ni)
#pragma unroll
      for (int r = 0; r < 4; ++r) {
        int gm = m0 + wr*64 + mi*16 + ((l >> 4) << 2) + r;
        int hd = hd0 + ni*16 + (l & 15);
        float v = acc[mi][ni][r] + bp[hd];
        size_t off = ((size_t)((gm >> 11)*H_ + (hd >> 6)) * S_ + (gm & 2047)) * 64 + (hd & 63);
        ob[off] = f2bf(v);
      }
}

// ---------------- NT GEMM: C[m,n] = sum_k A[m,k]*B[n,k] (K=1024) ----------------
template<int EPI>
__global__ __launch_bounds__(256)
void gemm_nt(const unsigned short* __restrict__ A,
             const unsigned short* __restrict__ Bm,
             const float* __restrict__ bias,
             const float* __restrict__ resid,
             void* __restrict__ outp,
             int nbn) {
  __shared__ __attribute__((aligned(16))) short As[64*64];
  __shared__ __attribute__((aligned(16))) short Bs[128*64];
  int nwg = gridDim.x;
  int bid = blockIdx.x;
  int cpx = nwg >> 3;                                // grid % 8 == 0
  int sbid = (bid & 7) * cpx + (bid >> 3);
  int bm = sbid / nbn, bn = sbid % nbn;
  int m0 = bm << 6, n0 = bn << 7;
  int t = threadIdx.x;
  int l = t & 63, wid = t >> 6;

  int r_st = t >> 3;                                 // 0..31
  int slot_src = (t & 7) ^ (r_st & 7);               // pre-swizzled source slot
  const unsigned short* a_src = A + (size_t)(m0 + r_st) * KDIM + slot_src * 8;
  const unsigned short* b_src = Bm + (size_t)(n0 + r_st) * KDIM + slot_src * 8;
  char* As_base = (char*)As + wid*1024;
  char* Bs_base = (char*)Bs + wid*1024;

  f32x4 acc[4][2] = {};

  for (int kt = 0; kt < KDIM; kt += 64) {
    __syncthreads();
    glds16(a_src + kt, As_base);
    glds16(a_src + (size_t)32*KDIM + kt, As_base + 4096);
#pragma unroll
    for (int i = 0; i < 4; ++i)
      glds16(b_src + (size_t)(i*32)*KDIM + kt, Bs_base + i*4096);
    __syncthreads();
#pragma unroll
    for (int kk = 0; kk < 2; ++kk) {
      short8_t af[4], bfr[2];
#pragma unroll
      for (int mi = 0; mi < 4; ++mi) {
        int row = mi*16 + (l & 15);
        int slot = (kk*4 + (l >> 4)) ^ (row & 7);
        af[mi] = *(const short8_t*)((const char*)As + row*128 + slot*16);
      }
#pragma unroll
      for (int ni = 0; ni < 2; ++ni) {
        int row = wid*32 + ni*16 + (l & 15);
        int slot = (kk*4 + (l >> 4)) ^ (row & 7);
        bfr[ni] = *(const short8_t*)((const char*)Bs + row*128 + slot*16);
      }
#pragma unroll
      for (int mi = 0; mi < 4; ++mi)
#pragma unroll
        for (int ni = 0; ni < 2; ++ni)
          acc[mi][ni] = __builtin_amdgcn_mfma_f32_16x16x32_bf16(af[mi], bfr[ni], acc[mi][ni], 0, 0, 0);
    }
  }

#pragma unroll
  for (int mi = 0; mi < 4; ++mi) {
#pragma unroll
    for (int ni = 0; ni < 2; ++ni) {
#pragma unroll
      for (int r = 0; r < 4; ++r) {
        int gm = m0 + mi*16 + ((l >> 4) << 2) + r;
        int gn = n0 + wid*32 + ni*16 + (l & 15);
        float v = acc[mi][ni][r];
        v += bias[gm];
        size_t off = (size_t)(gn >> 11) * ((size_t)C_*S_) + (size_t)gm * S_ + (gn & 2047);
        if (EPI == 1) {
          ((unsigned short*)outp)[off] = f2bf(v);
        } else {
          ((float*)outp)[off] = v + resid[off];
        }
      }
    }
  }
}

// ---------------- flash attention, swapped 32x32, split-KV 8-wave -------------
// Q,K: (B,H,S,D) bf16; Vt: (B,H,D,S) bf16; out ao: (B,S,C) bf16
__global__ __launch_bounds__(512, 4)
void attn_kernel(const unsigned short* __restrict__ Q,
                 const unsigned short* __restrict__ Kt,
                 const unsigned short* __restrict__ Vt,
                 const int* __restrict__ mask,
                 unsigned short* __restrict__ outp) {
  // layout: K: quad*16384 + buf*8192 + row*128 + slot*16 ; V: +32768 same
  __shared__ __attribute__((aligned(16))) char lds[65536];
  __shared__ __attribute__((aligned(8)))  unsigned char maskb[256];
  __shared__ int tflag[32];

  int bid = blockIdx.x;                              // 512 blocks
  int bid2 = (bid & 7) * 64 + (bid >> 3);            // XCD swizzle (bijective)
  int bh = bid2 >> 4, qt = bid2 & 15;
  int b = bh >> 4, h = bh & 15;
  int t = threadIdx.x, l = t & 63, wid = t >> 6;
  int quad = wid >> 2, qw = wid & 3;
  int hh = l >> 5;                                   // half-lane index

  // ---- mask prologue: thread t<256 packs ints [8t, 8t+8) into byte t ----
  if (t < 256) {
    const i32x4* mp = (const i32x4*)(mask + b * S_) + t * 2;
    i32x4 m0 = mp[0], m1 = mp[1];
    unsigned by = (unsigned)(m0[0]!=0) | ((unsigned)(m0[1]!=0)<<1) | ((unsigned)(m0[2]!=0)<<2) | ((unsigned)(m0[3]!=0)<<3)
                | ((unsigned)(m1[0]!=0)<<4) | ((unsigned)(m1[1]!=0)<<5) | ((unsigned)(m1[2]!=0)<<6) | ((unsigned)(m1[3]!=0)<<7);
    maskb[t] = (unsigned char)by;
  }
  __syncthreads();
  if (t < 32) {
    unsigned long long v = ((const unsigned long long*)maskb)[t];
    tflag[t] = (v == 0xFFFFFFFFFFFFFFFFull) ? 1 : 0;
  }
  // visible after the first tile barrier

  // ---- Q fragments (B-operand): q-col = l&31, d = 16c + 8hh + j ----
  int q0 = qt*128 + qw*32;
  const unsigned short* qp = Q + ((size_t)bh * S_ + q0 + (l & 31)) * 64 + hh * 8;
  short8_t qf[4];
#pragma unroll
  for (int c = 0; c < 4; ++c) qf[c] = *(const short8_t*)(qp + c*16);

  // ---- staging: wave stages 16 K-rows + 16 V-rows of its quad's tile ----
  int kbase = quad << 10;
  int row_st = qw*16 + (l >> 3);
  int slot_st = (l & 7) ^ (l >> 3);
  const unsigned short* kp = Kt + ((size_t)bh * S_ + kbase + row_st) * 64 + slot_st * 8;
  const unsigned short* vp = Vt + ((size_t)bh * 64 + row_st) * S_ + kbase + slot_st * 8;
  char* kdst = lds + quad*16384 + qw*2048;
  char* vdst = kdst + 32768;

  // ---- ds-read byte offsets (tile-invariant; buf parity folds to imm) ----
  unsigned ko[8];
#pragma unroll
  for (int c = 0; c < 4; ++c) {
    unsigned slot = (unsigned)((c*2 + hh) ^ (l & 7)) * 16u;
    ko[c]   = (unsigned)(quad*16384) + (unsigned)(l & 31)*128u + slot;
    ko[c+4] = ko[c] + 4096u;
  }

  const short8_t vones = {0x3F80, 0x3F80, 0x3F80, 0x3F80, 0x3F80, 0x3F80, 0x3F80, 0x3F80};
  const float SC = 0.18033688011112042f;             // (1/8) * log2(e)
  float m_run = 0.f, msc = 0.f;
  f32x16 oc0 = {}, oc1 = {}, lsum = {};

  // prologue: stage tile 0 into buffer 0
  glds16(kp,                kdst);
  glds16(kp + 8*64,         kdst + 1024);
  glds16(vp,                vdst);
  glds16(vp + (size_t)8*S_, vdst + 1024);
  const unsigned short* kn = kp + 64*64;
  const unsigned short* vn = vp + 64;
  int lt = 0;

#define ATILE(BUF)                                                              \
  do {                                                                          \
    __syncthreads();                                                            \
    glds16(kn,                kdst + ((BUF)^1)*8192);                           \
    glds16(kn + 8*64,         kdst + ((BUF)^1)*8192 + 1024);                    \
    glds16(vn,                vdst + ((BUF)^1)*8192);                           \
    glds16(vn + (size_t)8*S_, vdst + ((BUF)^1)*8192 + 1024);                    \
    kn += 4096; vn += 64;                                                       \
    f32x16 st0 = {}, st1 = {};                                                  \
    __builtin_amdgcn_s_setprio(1);                                              \
    _Pragma("unroll")                                                           \
    for (int c = 0; c < 4; ++c) {                                               \
      short8_t kf0 = *(const short8_t*)(lds + ko[c]   + (BUF)*8192);            \
      short8_t kf1 = *(const short8_t*)(lds + ko[c+4] + (BUF)*8192);            \
      st0 = __builtin_amdgcn_mfma_f32_32x32x16_bf16(kf0, qf[c], st0, 0, 0, 0);  \
      st1 = __builtin_amdgcn_mfma_f32_32x32x16_bf16(kf1, qf[c], st1, 0, 0, 0);  \
    }                                                                           \
    __builtin_amdgcn_s_setprio(0);                                              \
    _Pragma("unroll")                                                           \
    for (int r = 0; r < 16; ++r) {                                              \
      st0[r] = __builtin_amdgcn_exp2f(fmaf(st0[r], SC, -msc));                  \
      st1[r] = __builtin_amdgcn_exp2f(fmaf(st1[r], SC, -msc));                  \
    }                                                                           \
    if (!tflag[(kbase >> 6) + lt]) {                                            \
      _Pragma("unroll")                                                         \
      for (int r = 0; r < 16; ++r) {                                            \
        int kl = kbase + lt*64 + (r & 3) + 8*(r >> 2) + 4*hh;                   \
        if (!((maskb[kl >> 3] >> (kl & 7)) & 1)) st0[r] = 0.f;                  \
        kl += 32;                                                               \
        if (!((maskb[kl >> 3] >> (kl & 7)) & 1)) st1[r] = 0.f;                  \
      }                                                                         \
    }                                                                           \
    float pmax = fmaxf(max16v(st0), max16v(st1));                               \
    short8_t pa[4];                                                             \
    {                                                                           \
      unsigned a0 = pkbf(st0[0],  st0[1]),  b0 = pkbf(st0[4],  st0[5]);         \
      unsigned a1 = pkbf(st0[2],  st0[3]),  b1 = pkbf(st0[6],  st0[7]);         \
      plswap(a0, b0); plswap(a1, b1);                                           \
      i32x4 w0 = {(int)a0, (int)a1, (int)b0, (int)b1};                          \
      pa[0] = __builtin_bit_cast(short8_t, w0);                                 \
      unsigned a2 = pkbf(st0[8],  st0[9]),  b2 = pkbf(st0[12], st0[13]);        \
      unsigned a3 = pkbf(st0[10], st0[11]), b3 = pkbf(st0[14], st0[15]);        \
      plswap(a2, b2); plswap(a3, b3);                                           \
      i32x4 w1 = {(int)a2, (int)a3, (int)b2, (int)b3};                          \
      pa[1] = __builtin_bit_cast(short8_t, w1);                                 \
      unsigned a4 = pkbf(st1[0],  st1[1]),  b4 = pkbf(st1[4],  st1[5]);         \
      unsigned a5 = pkbf(st1[2],  st1[3]),  b5 = pkbf(st1[6],  st1[7]);         \
      plswap(a4, b4); plswap(a5, b5);                                           \
      i32x4 w2 = {(int)a4, (int)a5, (int)b4, (int)b5};                          \
      pa[2] = __builtin_bit_cast(short8_t, w2);                                 \
      unsigned a6 = pkbf(st1[8],  st1[9]),  b6 = pkbf(st1[12], st1[13]);        \
      unsigned a7 = pkbf(st1[10], st1[11]), b7 = pkbf(st1[14], st1[15]);        \
      plswap(a6, b6); plswap(a7, b7);                                           \
      i32x4 w3 = {(int)a6, (int)a7, (int)b6, (int)b7};                          \
      pa[3] = __builtin_bit_cast(short8_t, w3);                                 \
    }                                                                           \
    __builtin_amdgcn_s_setprio(1);                                              \
    _Pragma("unroll")                                                           \
    for (int kc = 0; kc < 4; ++kc) {                                            \
      short8_t vf0 = *(const short8_t*)(lds + ko[kc]   + 32768 + (BUF)*8192);   \
      short8_t vf1 = *(const short8_t*)(lds + ko[kc+4] + 32768 + (BUF)*8192);   \
      oc0 = __builtin_amdgcn_mfma_f32_32x32x16_bf16(vf0, pa[kc], oc0, 0, 0, 0); \
      oc1 = __builtin_amdgcn_mfma_f32_32x32x16_bf16(vf1, pa[kc], oc1, 0, 0, 0); \
      lsum = __builtin_amdgcn_mfma_f32_32x32x16_bf16(vones, pa[kc], lsum, 0, 0, 0); \
    }                                                                           \
    __builtin_amdgcn_s_setprio(0);                                              \
    if (__any(pmax > 148.0f)) {                                                 \
      float pm = fmaxf(pmax, __shfl_xor(pmax, 32));                             \
      float smax = (__log2f(pm) + msc) / SC;                                    \
      float nm = fmaxf(m_run, smax);                                            \
      float fac = __builtin_amdgcn_exp2f((m_run - nm) * SC);                    \
      _Pragma("unroll")                                                         \
      for (int r = 0; r < 16; ++r) { oc0[r] *= fac; oc1[r] *= fac; lsum[r] *= fac; } \
      m_run = nm; msc = nm * SC;                                                \
    }                                                                           \
    ++lt;                                                                       \
  } while (0)

  for (int tp = 0; tp < 8; ++tp) {
    ATILE(0);
    ATILE(1);
  }
#undef ATILE

  // ---- merge epilogue: quad1 -> LDS, quad0 combines + stores ----
  __syncthreads();                                   // also drains garbage glds
  if (quad == 1) {
    char* obuf = lds + qw*8192 + l*128;
#pragma unroll
    for (int j = 0; j < 4; ++j) {
      f32x4 u0 = { oc0[4*j], oc0[4*j+1], oc0[4*j+2], oc0[4*j+3] };
      *(f32x4*)(obuf + ((j ^ (l & 7)) * 16)) = u0;
      f32x4 u1 = { oc1[4*j], oc1[4*j+1], oc1[4*j+2], oc1[4*j+3] };
      *(f32x4*)(obuf + (((j+4) ^ (l & 7)) * 16)) = u1;
    }
    *(float2*)(lds + 32768 + (qw*64 + l)*8) = make_float2(lsum[0], m_run);
  }
  __syncthreads();
  if (quad == 0) {
    float2 lm1 = *(const float2*)(lds + 32768 + (qw*64 + l)*8);
    float M  = fmaxf(m_run, lm1.y);
    float a0 = __builtin_amdgcn_exp2f((m_run - M) * SC);
    float a1 = __builtin_amdgcn_exp2f((lm1.y - M) * SC);
    float lc = lsum[0] * a0 + lm1.x * a1;
    float inv = 1.f / lc;
    float s0 = a0 * inv, s1 = a1 * inv;
    const char* obuf = lds + qw*8192 + l*128;
#pragma unroll
    for (int j = 0; j < 4; ++j) {
      f32x4 u0 = *(const f32x4*)(obuf + ((j ^ (l & 7)) * 16));
      oc0[4*j]   = oc0[4*j]  *s0 + u0[0]*s1;
      oc0[4*j+1] = oc0[4*j+1]*s0 + u0[1]*s1;
      oc0[4*j+2] = oc0[4*j+2]*s0 + u0[2]*s1;
      oc0[4*j+3] = oc0[4*j+3]*s0 + u0[3]*s1;
      f32x4 u1 = *(const f32x4*)(obuf + (((j+4) ^ (l & 7)) * 16));
      oc1[4*j]   = oc1[4*j]  *s0 + u1[0]*s1;
      oc1[4*j+1] = oc1[4*j+1]*s0 + u1[1]*s1;
      oc1[4*j+2] = oc1[4*j+2]*s0 + u1[2]*s1;
      oc1[4*j+3] = oc1[4*j+3]*s0 + u1[3]*s1;
    }

    unsigned short* obase = outp + ((size_t)b * S_ + q0 + (l & 31)) * C_ + h*64 + hh*8;
#pragma unroll
    for (int dt = 0; dt < 2; ++dt) {
      const f32x16& oc = dt ? oc1 : oc0;
      unsigned a0w = pkbf(oc[0],  oc[1]),  b0w = pkbf(oc[4],  oc[5]);
      unsigned a1w = pkbf(oc[2],  oc[3]),  b1w = pkbf(oc[6],  oc[7]);
      plswap(a0w, b0w); plswap(a1w, b1w);
      i32x4 w0 = {(int)a0w, (int)a1w, (int)b0w, (int)b1w};
      *(i32x4*)(obase + dt*32) = w0;
      unsigned a2w = pkbf(oc[8],  oc[9]),  b2w = pkbf(oc[12], oc[13]);
      unsigned a3w = pkbf(oc[10], oc[11]), b3w = pkbf(oc[14], oc[15]);
      plswap(a2w, b2w); plswap(a3w, b3w);
      i32x4 w1 = {(int)a2w, (int)a3w, (int)b2w, (int)b3w};
      *(i32x4*)(obase + dt*32 + 16) = w1;
    }
  }
}

// ---------------- launcher ----------------
extern "C" void kernel_launch(void* const* d_in, const int* in_sizes, int n_in,
                              void* d_out, int out_size, void* d_ws, size_t ws_size,
                              hipStream_t stream) {
  const float* hs = (const float*)d_in[0];
  const int*   msk = (const int*)d_in[1];
  const float* gw = (const float*)d_in[2];
  const float* gb = (const float*)d_in[3];
  const float* Wq = (const float*)d_in[4];
  const float* bq = (const float*)d_in[5];
  const float* Wk = (const float*)d_in[6];
  const float* bk = (const float*)d_in[7];
  const float* Wv = (const float*)d_in[8];
  const float* bv = (const float*)d_in[9];
  const float* Wo = (const float*)d_in[10];
  const float* bo = (const float*)d_in[11];

  char* ws = (char*)d_ws;
  float*  stats = (float*)(ws);
  float2* part  = (float2*)(ws + 256);
  unsigned short* wq_b = (unsigned short*)(ws + 8192);
  unsigned short* wk_b = wq_b + 1048576;
  unsigned short* wv_b = wk_b + 1048576;
  unsigned short* wo_b = wv_b + 1048576;
  unsigned short* x_b  = wo_b + 1048576;     // (B,S,C) bf16
  unsigned short* q_b  = x_b  + 4194304;     // (B,H,S,D)
  unsigned short* k_b  = q_b  + 4194304;     // (B,H,S,D)
  unsigned short* vt_b = k_b  + 4194304;     // (B,H,D,S)
  unsigned short* ao_b = vt_b + 4194304;     // (B,S,C)

  cvt_w4<<<4096, 256, 0, stream>>>(Wq, Wk, Wv, Wo, wq_b);

  stats1<<<512, 256, 0, stream>>>(hs, part);
  stats2<<<2, 256, 0, stream>>>(part, stats);
  normt<<<1024, 256, 0, stream>>>(hs, gw, gb, stats, x_b);

  gemm_qk<<<512, 256, 0, stream>>>(x_b, wq_b, bq, bk, q_b);
  gemm_nt<1><<<512, 256, 0, stream>>>(wv_b, x_b, bv, nullptr, vt_b, 32);

  attn_kernel<<<512, 512, 0, stream>>>(q_b, k_b, vt_b, msk, ao_b);

  gemm_nt<2><<<512, 256, 0, stream>>>(wo_b, ao_b, bo, hs, d_out, 32);
}